// Round 12
// baseline (310.124 us; speedup 1.0000x reference)
//
#include <hip/hip_runtime.h>
#include <hip/hip_bf16.h>

typedef __bf16 bf16;
using bf16x8 = __attribute__((ext_vector_type(8))) __bf16;
using bf16x4 = __attribute__((ext_vector_type(4))) __bf16;
using f32x4  = __attribute__((ext_vector_type(4))) float;
using f32x16 = __attribute__((ext_vector_type(16))) float;

#define DEV __device__ __forceinline__

DEV void load_lds16(const void* g, void* l) {
  __builtin_amdgcn_global_load_lds(
      (const __attribute__((address_space(1))) void*)g,
      (__attribute__((address_space(3))) void*)l, 16, 0, 0);
}

// ---------------- RoPE table: (cos,sin) [2048][64] float2 (double-accurate) ------------
__global__ void k_tab(float2* __restrict__ cst) {
  int l = blockIdx.x, i = threadIdx.x;  // 2048 x 64
  double invf = pow(10000.0, -(double)i / 64.0);
  double a = (double)l * invf;
  cst[l * 64 + i] = make_float2((float)cos(a), (float)sin(a));
}

// ---------------- f32 -> bf16 bulk convert ----------------
__global__ void k_f2b(const float* __restrict__ in, bf16* __restrict__ out, long n) {
  long i = ((long)blockIdx.x * blockDim.x + threadIdx.x) * 8;
  if (i >= n) return;
  float4 a = *(const float4*)(in + i);
  float4 b = *(const float4*)(in + i + 4);
  bf16x8 o;
  o[0] = (bf16)a.x; o[1] = (bf16)a.y; o[2] = (bf16)a.z; o[3] = (bf16)a.w;
  o[4] = (bf16)b.x; o[5] = (bf16)b.y; o[6] = (bf16)b.z; o[7] = (bf16)b.w;
  *(bf16x8*)(out + i) = o;
}

// ---------------- transpose+convert: f32 [R][C] -> bf16 [C][R] (R,C mult of 64) --------
__global__ __launch_bounds__(256) void k_tconv(const float* __restrict__ in,
                                               bf16* __restrict__ out, int R, int C) {
  __shared__ float t[64][65];
  int nbc = C >> 6;
  long r0 = (long)(blockIdx.x / nbc) * 64, c0 = (long)(blockIdx.x % nbc) * 64;
  int tid = threadIdx.x;
#pragma unroll
  for (int i = 0; i < 4; ++i) {
    int ch = tid + i * 256;
    int r = ch >> 4, c4 = (ch & 15) * 4;
    float4 v = *(const float4*)(in + (r0 + r) * C + c0 + c4);
    t[r][c4] = v.x; t[r][c4 + 1] = v.y; t[r][c4 + 2] = v.z; t[r][c4 + 3] = v.w;
  }
  __syncthreads();
#pragma unroll
  for (int i = 0; i < 2; ++i) {
    int ch = tid + i * 256;
    int c = ch >> 3, r8 = (ch & 7) * 8;
    bf16x8 o;
#pragma unroll
    for (int j = 0; j < 8; ++j) o[j] = (bf16)t[r8 + j][c];
    *(bf16x8*)(out + (c0 + c) * R + r0 + r8) = o;
  }
}

// ------- m97-style GEMM, BK=64 + XOR-swizzled LDS (R6 proven, 841 TF) ------------------
// fuse=1 (QKV): epilogue stages C tile (bias added, bf16) into dead LDS; q/k heads get
// RoPE+RMSNorm -> q_r/k_r, v heads get transpose -> v_t. fuse=0: plain C write.
// Epilogue loops are PARTIALLY unrolled (2 / 4) to cap register pressure: full unroll
// cost +24 VGPR -> lost a resident block -> main-loop MfmaUtil 37->29 (R10/R11 counters).
template <typename OutT>
__global__ __launch_bounds__(256) void k_gemm_bt(
    const bf16* __restrict__ A, const bf16* __restrict__ Bt,
    const float* __restrict__ bias, OutT* __restrict__ C,
    int M, int N, int K, int fuse,
    const float2* __restrict__ cst,
    const float* __restrict__ qw, const float* __restrict__ kw,
    bf16* __restrict__ q_r, bf16* __restrict__ k_r, bf16* __restrict__ v_t) {
  __shared__ __align__(16) bf16 lAB[2][128 * 64];   // contiguous: epilogue reuses as [128][128]
  bf16* lA = lAB[0];
  bf16* lB = lAB[1];
  int bid = blockIdx.x;
  if ((gridDim.x & 7) == 0) {  // XCD-aware swizzle (bijective: nwg % 8 == 0)
    int q = gridDim.x >> 3;
    bid = (bid & 7) * q + (bid >> 3);
  }
  int nbn = N >> 7;
  int bm = bid / nbn, bn = bid % nbn;
  const int tid = threadIdx.x, lane = tid & 63, wid = tid >> 6;
  const int wr = wid >> 1, wc = wid & 1;
  const int fr = lane & 15, fq = lane >> 4;
  const long abase = (long)bm * 128 * K, bbase = (long)bn * 128 * K;
  f32x4 acc[4][4] = {};

  for (int k0 = 0; k0 < K; k0 += 64) {
    __syncthreads();
#pragma unroll
    for (int it = 0; it < 4; ++it) {
      int ch = it * 256 + tid;          // 1024 chunks of 16B = [128][64] bf16
      int r = ch >> 3, u = ch & 7;
      load_lds16(A + abase + (long)r * K + k0 + ((u ^ (r & 7)) << 3), &lA[ch * 8]);
    }
#pragma unroll
    for (int it = 0; it < 4; ++it) {
      int ch = it * 256 + tid;
      int r = ch >> 3, u = ch & 7;
      load_lds16(Bt + bbase + (long)r * K + k0 + ((u ^ (r & 7)) << 3), &lB[ch * 8]);
    }
    __syncthreads();
    bf16x8 af[4][2], bf_[4][2];
#pragma unroll
    for (int m = 0; m < 4; ++m) {
      int R = wr * 64 + m * 16 + fr;
#pragma unroll
      for (int kk = 0; kk < 2; ++kk)
        af[m][kk] = *(const bf16x8*)&lA[R * 64 + (((kk * 4 + fq) ^ (R & 7)) << 3)];
    }
#pragma unroll
    for (int n = 0; n < 4; ++n) {
      int R = wc * 64 + n * 16 + fr;
#pragma unroll
      for (int kk = 0; kk < 2; ++kk)
        bf_[n][kk] = *(const bf16x8*)&lB[R * 64 + (((kk * 4 + fq) ^ (R & 7)) << 3)];
    }
#pragma unroll
    for (int m = 0; m < 4; ++m)
#pragma unroll
      for (int n = 0; n < 4; ++n)
#pragma unroll
        for (int kk = 0; kk < 2; ++kk)
          acc[m][n] = __builtin_amdgcn_mfma_f32_16x16x32_bf16(af[m][kk], bf_[n][kk],
                                                              acc[m][n], 0, 0, 0);
  }

  if (!fuse) {
#pragma unroll
    for (int n = 0; n < 4; ++n) {
      int col = bn * 128 + wc * 64 + n * 16 + fr;
      float bv = bias[col];
#pragma unroll
      for (int m = 0; m < 4; ++m) {
        int row0 = bm * 128 + wr * 64 + m * 16 + fq * 4;
#pragma unroll
        for (int r = 0; r < 4; ++r) {
          float v = acc[m][n][r] + bv;
          C[(long)(row0 + r) * N + col] = (OutT)v;
        }
      }
    }
    return;
  }

  // ---------------- fused epilogue (QKV: N=6144, bn 0-15 q / 16-31 k / 32-47 v) --------
  __syncthreads();                       // all waves done with lA/lB fragment reads
  bf16* tile = lAB[0];                   // [128][128] bf16, XOR-swizzled per mode
  const int h = bn & 15;
  const int b = bm >> 4, l0 = (bm & 15) << 7;

  if (bn < 32) {
    // store tile[row][col ^ ((row&7)<<3)]  (row = l-local, col = d)
#pragma unroll
    for (int n = 0; n < 4; ++n) {
      int col = wc * 64 + n * 16 + fr;
      float bv = bias[bn * 128 + col];
#pragma unroll
      for (int m = 0; m < 4; ++m)
#pragma unroll
        for (int r = 0; r < 4; ++r) {
          int row = wr * 64 + m * 16 + fq * 4 + r;
          tile[row * 128 + (col ^ ((row & 7) << 3))] = (bf16)(acc[m][n][r] + bv);
        }
    }
    __syncthreads();
    const float* wv = (bn < 16) ? qw : kw;
    bf16* dst0 = (bn < 16) ? q_r : k_r;
    const int tcol = tid & 15, rgrp = tid >> 4, i8 = tcol * 8;
    const bool lo = i8 < 64;
    float wvv[8];
#pragma unroll
    for (int j = 0; j < 8; ++j) wvv[j] = wv[i8 + j];
#pragma unroll 2
    for (int it = 0; it < 8; ++it) {
      int row = it * 16 + rgrp;
      int l = l0 + row;
      float cc[8], sn[8];
#pragma unroll
      for (int j = 0; j < 8; ++j) {
        int d = (i8 + j) & 63;
        float2 cs = cst[l * 64 + d];
        cc[j] = cs.x;
        sn[j] = cs.y;
      }
      bf16x8 xv = *(const bf16x8*)&tile[row * 128 + (i8 ^ ((row & 7) << 3))];
      float v[8], p[8], rr[8];
      float ss = 0.f;
#pragma unroll
      for (int j = 0; j < 8; ++j) v[j] = (float)xv[j];
#pragma unroll
      for (int j = 0; j < 8; ++j) p[j] = __shfl_xor(v[j], 8);  // d <-> d^64
#pragma unroll
      for (int j = 0; j < 8; ++j) {
        rr[j] = lo ? v[j] * cc[j] - p[j] * sn[j] : v[j] * cc[j] + p[j] * sn[j];
        ss += rr[j] * rr[j];
      }
      ss += __shfl_xor(ss, 1);
      ss += __shfl_xor(ss, 2);
      ss += __shfl_xor(ss, 4);
      ss += __shfl_xor(ss, 8);
      float inv = rsqrtf(ss * (1.f / 128.f) + 1e-6f);
      bf16x8 ov;
#pragma unroll
      for (int j = 0; j < 8; ++j) ov[j] = (bf16)(rr[j] * inv * wvv[j]);
      *(bf16x8*)(dst0 + ((long)((b * 16 + h) * 2048 + l)) * 128 + i8) = ov;
    }
  } else {
    // v: store transposed tile[col][row ^ ((col&7)<<3)]  (col = d, row = l-local)
#pragma unroll
    for (int n = 0; n < 4; ++n) {
      int col = wc * 64 + n * 16 + fr;
      float bv = bias[bn * 128 + col];
#pragma unroll
      for (int m = 0; m < 4; ++m)
#pragma unroll
        for (int r = 0; r < 4; ++r) {
          int row = wr * 64 + m * 16 + fq * 4 + r;
          tile[col * 128 + (row ^ ((col & 7) << 3))] = (bf16)(acc[m][n][r] + bv);
        }
    }
    __syncthreads();
    // coalesced write: 16 consecutive lanes cover one d-row's 256 B (vs 16B scatter)
    bf16* dstb = v_t + ((long)((b * 16 + h) * 128)) * 2048 + l0;
#pragma unroll 4
    for (int it = 0; it < 8; ++it) {
      int ch = it * 256 + tid;          // 2048 chunks of 16 B = [128 d][16 chunks]
      int d = ch >> 4, l8 = (ch & 15) * 8;
      bf16x8 vv = *(const bf16x8*)&tile[d * 128 + (l8 ^ ((d & 7) << 3))];
      *(bf16x8*)(dstb + (long)d * 2048 + l8) = vv;
    }
  }
}

// ---------------- flash attention v4 + head-locality swizzle (R11-proven) ----------------
__global__ __launch_bounds__(512, 2) void k_attn(
    const bf16* __restrict__ q_r, const bf16* __restrict__ k_r,
    const bf16* __restrict__ v_t, const unsigned char* __restrict__ amask,
    bf16* __restrict__ attno) {
  __shared__ __align__(16) bf16 lK[2][64 * 128];   // [kv][dh], XOR-swizzled (16B chunks)
  __shared__ __align__(16) bf16 lV[2][128 * 64];   // [dh][kv], XOR-swizzled
  __shared__ int sAny;
  const int tid = threadIdx.x, lane = tid & 63, w = tid >> 6;
  const int hi = lane >> 5, q31 = lane & 31;
  const int bh = blockIdx.x & 31, qt = blockIdx.x >> 5;
  const int b = bh >> 4, h = bh & 15;
  const long hbase = (long)bh * 2048 * 128;
  const int q0 = qt * 256 + w * 32;
  const unsigned char* mb = amask + b * 2048;

  if (tid == 0) sAny = 0;
  __syncthreads();
  {
    unsigned mv = *(const unsigned*)(mb + tid * 4);
    if (mv) sAny = 1;
  }

  // Q fragments (B-operand of 32x32x16): qf[ksl][j] = Q[q0+q31][ksl*16 + hi*8 + j]
  bf16x8 qf[8];
#pragma unroll
  for (int ksl = 0; ksl < 8; ++ksl)
    qf[ksl] = *(const bf16x8*)(q_r + hbase + (long)(q0 + q31) * 128 + ksl * 16 + hi * 8);

  f32x16 o[4] = {};          // o[dt][reg]: O[q=crow(reg,hi)][d=dt*32+q31]
  float m_run = -1e30f, l_run = 0.f;
  const float SC2 = 0.08838834764831845f * 1.4426950408889634f;  // 1/sqrt(128) * log2(e)
  const float L2E = 1.4426950408889634f;

#define STAGE(buf, kv0)                                                              \
  {                                                                                  \
    _Pragma("unroll") for (int it = 0; it < 2; ++it) {                               \
      int g = it * 512 + w * 64 + lane;                                              \
      int r = g >> 4, u = g & 15;                                                    \
      load_lds16(k_r + hbase + (long)((kv0) + r) * 128 + ((u ^ (r & 7)) << 3),       \
                 &lK[buf][(it * 512 + w * 64) * 8]);                                 \
    }                                                                                \
    _Pragma("unroll") for (int it = 0; it < 2; ++it) {                               \
      int g = it * 512 + w * 64 + lane;                                              \
      int r = g >> 3, u = g & 7;                                                     \
      load_lds16(v_t + hbase + (long)r * 2048 + (kv0) + ((u ^ (r & 7)) << 3),        \
                 &lV[buf][(it * 512 + w * 64) * 8]);                                 \
    }                                                                                \
  }

  STAGE(0, 0);
  __syncthreads();
  const bool maskAny = sAny != 0;
  int cur = 0;
  for (int t = 0; t < 32; ++t) {
    const int kv0 = t << 6;
    if (t < 31) STAGE(cur ^ 1, kv0 + 64);

    // ---- S^T = K Q^T : st0 = kv 0..31, st1 = kv 32..63; lane holds col q = q31 ----
    f32x16 st0 = {}, st1 = {};
#pragma unroll
    for (int ksl = 0; ksl < 8; ++ksl) {
      const int u = ksl * 2 + hi;
      bf16x8 kf0 = *(const bf16x8*)&lK[cur][q31 * 128 + ((u ^ (q31 & 7)) << 3)];
      bf16x8 kf1 = *(const bf16x8*)&lK[cur][(32 + q31) * 128 + ((u ^ (q31 & 7)) << 3)];
      st0 = __builtin_amdgcn_mfma_f32_32x32x16_bf16(kf0, qf[ksl], st0, 0, 0, 0);
      st1 = __builtin_amdgcn_mfma_f32_32x32x16_bf16(kf1, qf[ksl], st1, 0, 0, 0);
    }

#pragma unroll
    for (int i = 0; i < 16; ++i) { st0[i] *= SC2; st1[i] *= SC2; }
    if (maskAny) {
#pragma unroll
      for (int i = 0; i < 16; ++i) {
        int c = (i & 3) + 8 * (i >> 2) + 4 * hi;
        if (mb[kv0 + c]) st0[i] += L2E;
        if (mb[kv0 + 32 + c]) st1[i] += L2E;
      }
    }

    // ---- in-register row max (31 fmax + 1 shfl) ----
    float tm = st0[0];
#pragma unroll
    for (int i = 1; i < 16; ++i) tm = fmaxf(tm, st0[i]);
#pragma unroll
    for (int i = 0; i < 16; ++i) tm = fmaxf(tm, st1[i]);
    tm = fmaxf(tm, __shfl_xor(tm, 32));

    if (!__all(tm <= m_run + 8.f)) {  // T13 defer-max, THR=8 (factor 256 headroom)
      float mn = fmaxf(m_run, tm);
      float corr = exp2f(m_run - mn);
      m_run = mn;
      l_run *= corr;
#pragma unroll
      for (int i = 0; i < 16; ++i) {
        float cr = __shfl(corr, (i & 3) + 8 * (i >> 2) + 4 * hi);
#pragma unroll
        for (int dt = 0; dt < 4; ++dt) o[dt][i] *= cr;
      }
    }

    // ---- exp + row sum ----
    float rs = 0.f;
#pragma unroll
    for (int i = 0; i < 16; ++i) { st0[i] = exp2f(st0[i] - m_run); rs += st0[i]; }
#pragma unroll
    for (int i = 0; i < 16; ++i) { st1[i] = exp2f(st1[i] - m_run); rs += st1[i]; }
    rs += __shfl_xor(rs, 32);
    l_run += rs;

    // ---- P -> bf16 PV A-frags via packed half-swap ----
    union UU { bf16x4 v; uint2 u; };
    union U8 { bf16x8 v; uint4 u; };
    bf16x8 pa[4];
#define MKPA(pidx, STX, bb)                                                          \
  {                                                                                  \
    UU plo, phi;                                                                     \
    plo.v = (bf16x4){(bf16)STX[bb], (bf16)STX[(bb) + 1], (bf16)STX[(bb) + 2],        \
                     (bf16)STX[(bb) + 3]};                                           \
    phi.v = (bf16x4){(bf16)STX[(bb) + 4], (bf16)STX[(bb) + 5], (bf16)STX[(bb) + 6],  \
                     (bf16)STX[(bb) + 7]};                                           \
    unsigned sx = hi ? plo.u.x : phi.u.x, sy = hi ? plo.u.y : phi.u.y;               \
    unsigned rx = (unsigned)__shfl_xor((int)sx, 32), ry = (unsigned)__shfl_xor((int)sy, 32); \
    U8 f;                                                                            \
    f.u.x = hi ? rx : plo.u.x; f.u.y = hi ? ry : plo.u.y;                            \
    f.u.z = hi ? phi.u.x : rx; f.u.w = hi ? phi.u.y : ry;                            \
    pa[pidx] = f.v;                                                                  \
  }
    MKPA(0, st0, 0) MKPA(1, st0, 8) MKPA(2, st1, 0) MKPA(3, st1, 8)
#undef MKPA

    // ---- O += P V ----
#pragma unroll
    for (int dt = 0; dt < 4; ++dt) {
      const int dr = dt * 32 + q31;
#pragma unroll
      for (int ks = 0; ks < 4; ++ks) {
        const int u = ks * 2 + hi;
        bf16x8 vb = *(const bf16x8*)&lV[cur][dr * 64 + ((u ^ (dr & 7)) << 3)];
        o[dt] = __builtin_amdgcn_mfma_f32_32x32x16_bf16(pa[ks], vb, o[dt], 0, 0, 0);
      }
    }

    __syncthreads();  // drains this iter's STAGE vmcnt; all waves done reading cur
    cur ^= 1;
  }
#undef STAGE

  // ---- epilogue: 1/l via shfl, padding-row zero, store [B,L,H*DH] bf16 ----
  float invl = 1.f / l_run;
#pragma unroll
  for (int i = 0; i < 16; ++i) {
    int q = (i & 3) + 8 * (i >> 2) + 4 * hi;
    int qrow = q0 + q;
    float inv = __shfl(invl, q);
    float zm = inv;
    if (maskAny) { if (mb[qrow]) zm = 0.f; }
#pragma unroll
    for (int dt = 0; dt < 4; ++dt)
      attno[(long)(b * 2048 + qrow) * 2048 + h * 128 + dt * 32 + q31] = (bf16)(o[dt][i] * zm);
  }
}

extern "C" void kernel_launch(void* const* d_in, const int* in_sizes, int n_in,
                              void* d_out, int out_size, void* d_ws, size_t ws_size,
                              hipStream_t stream) {
  const float* x = (const float*)d_in[0];
  const unsigned char* amask = (const unsigned char*)d_in[1];
  const float* Wqkv = (const float*)d_in[2];
  const float* bqkv = (const float*)d_in[3];
  const float* Wout = (const float*)d_in[4];
  const float* bout = (const float*)d_in[5];
  const float* qw = (const float*)d_in[6];
  const float* kw = (const float*)d_in[7];
  float* out = (float*)d_out;
  char* ws = (char*)d_ws;

  bf16* xb   = (bf16*)(ws);                         // 16 MB (reused as attnout later)
  bf16* wqT  = (bf16*)(ws + 16777216);              // 24 MB  Wqkv^T [6144][2048]
  bf16* woT  = (bf16*)(ws + 41943040);              // 8 MB   Wout^T [2048][2048]
  bf16* q_r  = (bf16*)(ws + 100663296);             // 16 MB  [B*H,L,DH]
  bf16* k_r  = (bf16*)(ws + 117440512);             // 16 MB
  bf16* v_t  = (bf16*)(ws + 134217728);             // 16 MB  [B*H,DH,L]
  float2* cst = (float2*)(ws + 150994944);          // 1 MB   (cos,sin) packed
  bf16* attno = xb;  // alias: x_bf16 dead after QKV GEMM

  k_tab<<<2048, 64, 0, stream>>>(cst);
  k_f2b<<<4096, 256, 0, stream>>>(x, xb, 8388608L);
  k_tconv<<<32 * 96, 256, 0, stream>>>(Wqkv, wqT, 2048, 6144);
  k_tconv<<<32 * 32, 256, 0, stream>>>(Wout, woT, 2048, 2048);
  k_gemm_bt<bf16><<<32 * 48, 256, 0, stream>>>(xb, wqT, bqkv, (bf16*)nullptr,
                                               4096, 6144, 2048, 1,
                                               cst, qw, kw, q_r, k_r, v_t);
  k_attn<<<256, 512, 0, stream>>>(q_r, k_r, v_t, amask, attno);
  k_gemm_bt<float><<<32 * 16, 256, 0, stream>>>(attno, woT, bout, out,
                                                4096, 2048, 2048, 0,
                                                nullptr, nullptr, nullptr,
                                                nullptr, nullptr, nullptr);
}

// Round 13
// 309.261 us; speedup vs baseline: 1.0028x; 1.0028x over previous
//
#include <hip/hip_runtime.h>
#include <hip/hip_bf16.h>

typedef __bf16 bf16;
using bf16x8 = __attribute__((ext_vector_type(8))) __bf16;
using bf16x4 = __attribute__((ext_vector_type(4))) __bf16;
using f32x4  = __attribute__((ext_vector_type(4))) float;
using f32x16 = __attribute__((ext_vector_type(16))) float;

#define DEV __device__ __forceinline__

DEV void load_lds16(const void* g, void* l) {
  __builtin_amdgcn_global_load_lds(
      (const __attribute__((address_space(1))) void*)g,
      (__attribute__((address_space(3))) void*)l, 16, 0, 0);
}

// ---------------- RoPE inverse-frequency table: invf[64] f32 -------------------------
// invf matches the reference's fp32 inv_freq (correctly-rounded 10000^(i/64), recip).
__global__ void k_tab(float* __restrict__ invf) {
  int i = threadIdx.x;  // 64
  invf[i] = 1.0f / (float)pow(10000.0, (double)i / 64.0);
}

// ---------------- f32 -> bf16 bulk convert ----------------
__global__ void k_f2b(const float* __restrict__ in, bf16* __restrict__ out, long n) {
  long i = ((long)blockIdx.x * blockDim.x + threadIdx.x) * 8;
  if (i >= n) return;
  float4 a = *(const float4*)(in + i);
  float4 b = *(const float4*)(in + i + 4);
  bf16x8 o;
  o[0] = (bf16)a.x; o[1] = (bf16)a.y; o[2] = (bf16)a.z; o[3] = (bf16)a.w;
  o[4] = (bf16)b.x; o[5] = (bf16)b.y; o[6] = (bf16)b.z; o[7] = (bf16)b.w;
  *(bf16x8*)(out + i) = o;
}

// ---------------- transpose+convert: f32 [R][C] -> bf16 [C][R] (R,C mult of 64) --------
__global__ __launch_bounds__(256) void k_tconv(const float* __restrict__ in,
                                               bf16* __restrict__ out, int R, int C) {
  __shared__ float t[64][65];
  int nbc = C >> 6;
  long r0 = (long)(blockIdx.x / nbc) * 64, c0 = (long)(blockIdx.x % nbc) * 64;
  int tid = threadIdx.x;
#pragma unroll
  for (int i = 0; i < 4; ++i) {
    int ch = tid + i * 256;
    int r = ch >> 4, c4 = (ch & 15) * 4;
    float4 v = *(const float4*)(in + (r0 + r) * C + c0 + c4);
    t[r][c4] = v.x; t[r][c4 + 1] = v.y; t[r][c4 + 2] = v.z; t[r][c4 + 3] = v.w;
  }
  __syncthreads();
#pragma unroll
  for (int i = 0; i < 2; ++i) {
    int ch = tid + i * 256;
    int c = ch >> 3, r8 = (ch & 7) * 8;
    bf16x8 o;
#pragma unroll
    for (int j = 0; j < 8; ++j) o[j] = (bf16)t[r8 + j][c];
    *(bf16x8*)(out + (c0 + c) * R + r0 + r8) = o;
  }
}

// ------- m97-style GEMM, BK=64 + XOR-swizzled LDS (R6 proven, 841 TF) ------------------
// fuse=1 (QKV): epilogue stages C tile (bias added, bf16) into dead LDS; q/k heads get
// RoPE+RMSNorm -> q_r/k_r, v heads get transpose -> v_t. fuse=0: plain C write.
// RoPE cos/sin computed IN-REGISTER via __sincosf from a 64-float invf table (L1-hot):
// removes the per-row float2 table loads whose L3/HBM latency was exposed in R10-R12.
template <typename OutT>
__global__ __launch_bounds__(256) void k_gemm_bt(
    const bf16* __restrict__ A, const bf16* __restrict__ Bt,
    const float* __restrict__ bias, OutT* __restrict__ C,
    int M, int N, int K, int fuse,
    const float* __restrict__ invf,
    const float* __restrict__ qw, const float* __restrict__ kw,
    bf16* __restrict__ q_r, bf16* __restrict__ k_r, bf16* __restrict__ v_t) {
  __shared__ __align__(16) bf16 lAB[2][128 * 64];   // contiguous: epilogue reuses as [128][128]
  bf16* lA = lAB[0];
  bf16* lB = lAB[1];
  int bid = blockIdx.x;
  if ((gridDim.x & 7) == 0) {  // XCD-aware swizzle (bijective: nwg % 8 == 0)
    int q = gridDim.x >> 3;
    bid = (bid & 7) * q + (bid >> 3);
  }
  int nbn = N >> 7;
  int bm = bid / nbn, bn = bid % nbn;
  const int tid = threadIdx.x, lane = tid & 63, wid = tid >> 6;
  const int wr = wid >> 1, wc = wid & 1;
  const int fr = lane & 15, fq = lane >> 4;
  const long abase = (long)bm * 128 * K, bbase = (long)bn * 128 * K;
  f32x4 acc[4][4] = {};

  for (int k0 = 0; k0 < K; k0 += 64) {
    __syncthreads();
#pragma unroll
    for (int it = 0; it < 4; ++it) {
      int ch = it * 256 + tid;          // 1024 chunks of 16B = [128][64] bf16
      int r = ch >> 3, u = ch & 7;
      load_lds16(A + abase + (long)r * K + k0 + ((u ^ (r & 7)) << 3), &lA[ch * 8]);
    }
#pragma unroll
    for (int it = 0; it < 4; ++it) {
      int ch = it * 256 + tid;
      int r = ch >> 3, u = ch & 7;
      load_lds16(Bt + bbase + (long)r * K + k0 + ((u ^ (r & 7)) << 3), &lB[ch * 8]);
    }
    __syncthreads();
    bf16x8 af[4][2], bf_[4][2];
#pragma unroll
    for (int m = 0; m < 4; ++m) {
      int R = wr * 64 + m * 16 + fr;
#pragma unroll
      for (int kk = 0; kk < 2; ++kk)
        af[m][kk] = *(const bf16x8*)&lA[R * 64 + (((kk * 4 + fq) ^ (R & 7)) << 3)];
    }
#pragma unroll
    for (int n = 0; n < 4; ++n) {
      int R = wc * 64 + n * 16 + fr;
#pragma unroll
      for (int kk = 0; kk < 2; ++kk)
        bf_[n][kk] = *(const bf16x8*)&lB[R * 64 + (((kk * 4 + fq) ^ (R & 7)) << 3)];
    }
#pragma unroll
    for (int m = 0; m < 4; ++m)
#pragma unroll
      for (int n = 0; n < 4; ++n)
#pragma unroll
        for (int kk = 0; kk < 2; ++kk)
          acc[m][n] = __builtin_amdgcn_mfma_f32_16x16x32_bf16(af[m][kk], bf_[n][kk],
                                                              acc[m][n], 0, 0, 0);
  }

  if (!fuse) {
#pragma unroll
    for (int n = 0; n < 4; ++n) {
      int col = bn * 128 + wc * 64 + n * 16 + fr;
      float bv = bias[col];
#pragma unroll
      for (int m = 0; m < 4; ++m) {
        int row0 = bm * 128 + wr * 64 + m * 16 + fq * 4;
#pragma unroll
        for (int r = 0; r < 4; ++r) {
          float v = acc[m][n][r] + bv;
          C[(long)(row0 + r) * N + col] = (OutT)v;
        }
      }
    }
    return;
  }

  // ---------------- fused epilogue (QKV: N=6144, bn 0-15 q / 16-31 k / 32-47 v) --------
  __syncthreads();                       // all waves done with lA/lB fragment reads
  bf16* tile = lAB[0];                   // [128][128] bf16, XOR-swizzled per mode
  const int h = bn & 15;
  const int b = bm >> 4, l0 = (bm & 15) << 7;

  if (bn < 32) {
    // store tile[row][col ^ ((row&7)<<3)]  (row = l-local, col = d)
#pragma unroll
    for (int n = 0; n < 4; ++n) {
      int col = wc * 64 + n * 16 + fr;
      float bv = bias[bn * 128 + col];
#pragma unroll
      for (int m = 0; m < 4; ++m)
#pragma unroll
        for (int r = 0; r < 4; ++r) {
          int row = wr * 64 + m * 16 + fq * 4 + r;
          tile[row * 128 + (col ^ ((row & 7) << 3))] = (bf16)(acc[m][n][r] + bv);
        }
    }
    __syncthreads();
    const float* wv = (bn < 16) ? qw : kw;
    bf16* dst0 = (bn < 16) ? q_r : k_r;
    const int tcol = tid & 15, rgrp = tid >> 4, i8 = tcol * 8;
    const bool lo = i8 < 64;
    float wvv[8], invv[8];
#pragma unroll
    for (int j = 0; j < 8; ++j) wvv[j] = wv[i8 + j];
#pragma unroll
    for (int j = 0; j < 8; ++j) invv[j] = invf[(i8 + j) & 63];
#pragma unroll
    for (int it = 0; it < 8; ++it) {
      int row = it * 16 + rgrp;
      float fl = (float)(l0 + row);
      float cc[8], sn[8];
#pragma unroll
      for (int j = 0; j < 8; ++j) __sincosf(fl * invv[j], &sn[j], &cc[j]);
      bf16x8 xv = *(const bf16x8*)&tile[row * 128 + (i8 ^ ((row & 7) << 3))];
      float v[8], p[8], rr[8];
      float ss = 0.f;
#pragma unroll
      for (int j = 0; j < 8; ++j) v[j] = (float)xv[j];
#pragma unroll
      for (int j = 0; j < 8; ++j) p[j] = __shfl_xor(v[j], 8);  // d <-> d^64
#pragma unroll
      for (int j = 0; j < 8; ++j) {
        rr[j] = lo ? v[j] * cc[j] - p[j] * sn[j] : v[j] * cc[j] + p[j] * sn[j];
        ss += rr[j] * rr[j];
      }
      ss += __shfl_xor(ss, 1);
      ss += __shfl_xor(ss, 2);
      ss += __shfl_xor(ss, 4);
      ss += __shfl_xor(ss, 8);
      float inv = rsqrtf(ss * (1.f / 128.f) + 1e-6f);
      bf16x8 ov;
#pragma unroll
      for (int j = 0; j < 8; ++j) ov[j] = (bf16)(rr[j] * inv * wvv[j]);
      *(bf16x8*)(dst0 + ((long)((b * 16 + h) * 2048 + (l0 + row))) * 128 + i8) = ov;
    }
  } else {
    // v: store transposed tile[col][row ^ ((col&7)<<3)]  (col = d, row = l-local)
#pragma unroll
    for (int n = 0; n < 4; ++n) {
      int col = wc * 64 + n * 16 + fr;
      float bv = bias[bn * 128 + col];
#pragma unroll
      for (int m = 0; m < 4; ++m)
#pragma unroll
        for (int r = 0; r < 4; ++r) {
          int row = wr * 64 + m * 16 + fq * 4 + r;
          tile[col * 128 + (row ^ ((col & 7) << 3))] = (bf16)(acc[m][n][r] + bv);
        }
    }
    __syncthreads();
    // coalesced write: 16 consecutive lanes cover one d-row's 256 B (vs 16B scatter)
    bf16* dstb = v_t + ((long)((b * 16 + h) * 128)) * 2048 + l0;
#pragma unroll
    for (int it = 0; it < 8; ++it) {
      int ch = it * 256 + tid;          // 2048 chunks of 16 B = [128 d][16 chunks]
      int d = ch >> 4, l8 = (ch & 15) * 8;
      bf16x8 vv = *(const bf16x8*)&tile[d * 128 + (l8 ^ ((d & 7) << 3))];
      *(bf16x8*)(dstb + (long)d * 2048 + l8) = vv;
    }
  }
}

// ---------------- flash attention v4 + head-locality swizzle (R11-proven) ----------------
__global__ __launch_bounds__(512, 2) void k_attn(
    const bf16* __restrict__ q_r, const bf16* __restrict__ k_r,
    const bf16* __restrict__ v_t, const unsigned char* __restrict__ amask,
    bf16* __restrict__ attno) {
  __shared__ __align__(16) bf16 lK[2][64 * 128];   // [kv][dh], XOR-swizzled (16B chunks)
  __shared__ __align__(16) bf16 lV[2][128 * 64];   // [dh][kv], XOR-swizzled
  __shared__ int sAny;
  const int tid = threadIdx.x, lane = tid & 63, w = tid >> 6;
  const int hi = lane >> 5, q31 = lane & 31;
  const int bh = blockIdx.x & 31, qt = blockIdx.x >> 5;
  const int b = bh >> 4, h = bh & 15;
  const long hbase = (long)bh * 2048 * 128;
  const int q0 = qt * 256 + w * 32;
  const unsigned char* mb = amask + b * 2048;

  if (tid == 0) sAny = 0;
  __syncthreads();
  {
    unsigned mv = *(const unsigned*)(mb + tid * 4);
    if (mv) sAny = 1;
  }

  // Q fragments (B-operand of 32x32x16): qf[ksl][j] = Q[q0+q31][ksl*16 + hi*8 + j]
  bf16x8 qf[8];
#pragma unroll
  for (int ksl = 0; ksl < 8; ++ksl)
    qf[ksl] = *(const bf16x8*)(q_r + hbase + (long)(q0 + q31) * 128 + ksl * 16 + hi * 8);

  f32x16 o[4] = {};          // o[dt][reg]: O[q=crow(reg,hi)][d=dt*32+q31]
  float m_run = -1e30f, l_run = 0.f;
  const float SC2 = 0.08838834764831845f * 1.4426950408889634f;  // 1/sqrt(128) * log2(e)
  const float L2E = 1.4426950408889634f;

#define STAGE(buf, kv0)                                                              \
  {                                                                                  \
    _Pragma("unroll") for (int it = 0; it < 2; ++it) {                               \
      int g = it * 512 + w * 64 + lane;                                              \
      int r = g >> 4, u = g & 15;                                                    \
      load_lds16(k_r + hbase + (long)((kv0) + r) * 128 + ((u ^ (r & 7)) << 3),       \
                 &lK[buf][(it * 512 + w * 64) * 8]);                                 \
    }                                                                                \
    _Pragma("unroll") for (int it = 0; it < 2; ++it) {                               \
      int g = it * 512 + w * 64 + lane;                                              \
      int r = g >> 3, u = g & 7;                                                     \
      load_lds16(v_t + hbase + (long)r * 2048 + (kv0) + ((u ^ (r & 7)) << 3),        \
                 &lV[buf][(it * 512 + w * 64) * 8]);                                 \
    }                                                                                \
  }

  STAGE(0, 0);
  __syncthreads();
  const bool maskAny = sAny != 0;
  int cur = 0;
  for (int t = 0; t < 32; ++t) {
    const int kv0 = t << 6;
    if (t < 31) STAGE(cur ^ 1, kv0 + 64);

    // ---- S^T = K Q^T : st0 = kv 0..31, st1 = kv 32..63; lane holds col q = q31 ----
    f32x16 st0 = {}, st1 = {};
#pragma unroll
    for (int ksl = 0; ksl < 8; ++ksl) {
      const int u = ksl * 2 + hi;
      bf16x8 kf0 = *(const bf16x8*)&lK[cur][q31 * 128 + ((u ^ (q31 & 7)) << 3)];
      bf16x8 kf1 = *(const bf16x8*)&lK[cur][(32 + q31) * 128 + ((u ^ (q31 & 7)) << 3)];
      st0 = __builtin_amdgcn_mfma_f32_32x32x16_bf16(kf0, qf[ksl], st0, 0, 0, 0);
      st1 = __builtin_amdgcn_mfma_f32_32x32x16_bf16(kf1, qf[ksl], st1, 0, 0, 0);
    }

#pragma unroll
    for (int i = 0; i < 16; ++i) { st0[i] *= SC2; st1[i] *= SC2; }
    if (maskAny) {
#pragma unroll
      for (int i = 0; i < 16; ++i) {
        int c = (i & 3) + 8 * (i >> 2) + 4 * hi;
        if (mb[kv0 + c]) st0[i] += L2E;
        if (mb[kv0 + 32 + c]) st1[i] += L2E;
      }
    }

    // ---- in-register row max (31 fmax + 1 shfl) ----
    float tm = st0[0];
#pragma unroll
    for (int i = 1; i < 16; ++i) tm = fmaxf(tm, st0[i]);
#pragma unroll
    for (int i = 0; i < 16; ++i) tm = fmaxf(tm, st1[i]);
    tm = fmaxf(tm, __shfl_xor(tm, 32));

    if (!__all(tm <= m_run + 8.f)) {  // T13 defer-max, THR=8 (factor 256 headroom)
      float mn = fmaxf(m_run, tm);
      float corr = exp2f(m_run - mn);
      m_run = mn;
      l_run *= corr;
#pragma unroll
      for (int i = 0; i < 16; ++i) {
        float cr = __shfl(corr, (i & 3) + 8 * (i >> 2) + 4 * hi);
#pragma unroll
        for (int dt = 0; dt < 4; ++dt) o[dt][i] *= cr;
      }
    }

    // ---- exp + row sum ----
    float rs = 0.f;
#pragma unroll
    for (int i = 0; i < 16; ++i) { st0[i] = exp2f(st0[i] - m_run); rs += st0[i]; }
#pragma unroll
    for (int i = 0; i < 16; ++i) { st1[i] = exp2f(st1[i] - m_run); rs += st1[i]; }
    rs += __shfl_xor(rs, 32);
    l_run += rs;

    // ---- P -> bf16 PV A-frags via packed half-swap ----
    union UU { bf16x4 v; uint2 u; };
    union U8 { bf16x8 v; uint4 u; };
    bf16x8 pa[4];
#define MKPA(pidx, STX, bb)                                                          \
  {                                                                                  \
    UU plo, phi;                                                                     \
    plo.v = (bf16x4){(bf16)STX[bb], (bf16)STX[(bb) + 1], (bf16)STX[(bb) + 2],        \
                     (bf16)STX[(bb) + 3]};                                           \
    phi.v = (bf16x4){(bf16)STX[(bb) + 4], (bf16)STX[(bb) + 5], (bf16)STX[(bb) + 6],  \
                     (bf16)STX[(bb) + 7]};                                           \
    unsigned sx = hi ? plo.u.x : phi.u.x, sy = hi ? plo.u.y : phi.u.y;               \
    unsigned rx = (unsigned)__shfl_xor((int)sx, 32), ry = (unsigned)__shfl_xor((int)sy, 32); \
    U8 f;                                                                            \
    f.u.x = hi ? rx : plo.u.x; f.u.y = hi ? ry : plo.u.y;                            \
    f.u.z = hi ? phi.u.x : rx; f.u.w = hi ? phi.u.y : ry;                            \
    pa[pidx] = f.v;                                                                  \
  }
    MKPA(0, st0, 0) MKPA(1, st0, 8) MKPA(2, st1, 0) MKPA(3, st1, 8)
#undef MKPA

    // ---- O += P V ----
#pragma unroll
    for (int dt = 0; dt < 4; ++dt) {
      const int dr = dt * 32 + q31;
#pragma unroll
      for (int ks = 0; ks < 4; ++ks) {
        const int u = ks * 2 + hi;
        bf16x8 vb = *(const bf16x8*)&lV[cur][dr * 64 + ((u ^ (dr & 7)) << 3)];
        o[dt] = __builtin_amdgcn_mfma_f32_32x32x16_bf16(pa[ks], vb, o[dt], 0, 0, 0);
      }
    }

    __syncthreads();  // drains this iter's STAGE vmcnt; all waves done reading cur
    cur ^= 1;
  }
#undef STAGE

  // ---- epilogue: 1/l via shfl, padding-row zero, store [B,L,H*DH] bf16 ----
  float invl = 1.f / l_run;
#pragma unroll
  for (int i = 0; i < 16; ++i) {
    int q = (i & 3) + 8 * (i >> 2) + 4 * hi;
    int qrow = q0 + q;
    float inv = __shfl(invl, q);
    float zm = inv;
    if (maskAny) { if (mb[qrow]) zm = 0.f; }
#pragma unroll
    for (int dt = 0; dt < 4; ++dt)
      attno[(long)(b * 2048 + qrow) * 2048 + h * 128 + dt * 32 + q31] = (bf16)(o[dt][i] * zm);
  }
}

extern "C" void kernel_launch(void* const* d_in, const int* in_sizes, int n_in,
                              void* d_out, int out_size, void* d_ws, size_t ws_size,
                              hipStream_t stream) {
  const float* x = (const float*)d_in[0];
  const unsigned char* amask = (const unsigned char*)d_in[1];
  const float* Wqkv = (const float*)d_in[2];
  const float* bqkv = (const float*)d_in[3];
  const float* Wout = (const float*)d_in[4];
  const float* bout = (const float*)d_in[5];
  const float* qw = (const float*)d_in[6];
  const float* kw = (const float*)d_in[7];
  float* out = (float*)d_out;
  char* ws = (char*)d_ws;

  bf16* xb   = (bf16*)(ws);                         // 16 MB (reused as attnout later)
  bf16* wqT  = (bf16*)(ws + 16777216);              // 24 MB  Wqkv^T [6144][2048]
  bf16* woT  = (bf16*)(ws + 41943040);              // 8 MB   Wout^T [2048][2048]
  bf16* q_r  = (bf16*)(ws + 100663296);             // 16 MB  [B*H,L,DH]
  bf16* k_r  = (bf16*)(ws + 117440512);             // 16 MB
  bf16* v_t  = (bf16*)(ws + 134217728);             // 16 MB  [B*H,DH,L]
  float* invf = (float*)(ws + 150994944);           // 256 B
  bf16* attno = xb;  // alias: x_bf16 dead after QKV GEMM

  k_tab<<<1, 64, 0, stream>>>(invf);
  k_f2b<<<4096, 256, 0, stream>>>(x, xb, 8388608L);
  k_tconv<<<32 * 96, 256, 0, stream>>>(Wqkv, wqT, 2048, 6144);
  k_tconv<<<32 * 32, 256, 0, stream>>>(Wout, woT, 2048, 2048);
  k_gemm_bt<bf16><<<32 * 48, 256, 0, stream>>>(xb, wqT, bqkv, (bf16*)nullptr,
                                               4096, 6144, 2048, 1,
                                               invf, qw, kw, q_r, k_r, v_t);
  k_attn<<<256, 512, 0, stream>>>(q_r, k_r, v_t, amask, attno);
  k_gemm_bt<float><<<32 * 16, 256, 0, stream>>>(attno, woT, bout, out,
                                                4096, 2048, 2048, 0,
                                                nullptr, nullptr, nullptr,
                                                nullptr, nullptr, nullptr);
}

// Round 14
// 308.668 us; speedup vs baseline: 1.0047x; 1.0019x over previous
//
#include <hip/hip_runtime.h>
#include <hip/hip_bf16.h>

typedef __bf16 bf16;
using bf16x8 = __attribute__((ext_vector_type(8))) __bf16;
using bf16x4 = __attribute__((ext_vector_type(4))) __bf16;
using f32x4  = __attribute__((ext_vector_type(4))) float;
using f32x16 = __attribute__((ext_vector_type(16))) float;

#define DEV __device__ __forceinline__

DEV void load_lds16(const void* g, void* l) {
  __builtin_amdgcn_global_load_lds(
      (const __attribute__((address_space(1))) void*)g,
      (__attribute__((address_space(3))) void*)l, 16, 0, 0);
}

// ---------------- RoPE inverse-frequency table: invf[64] f32 -------------------------
__global__ void k_tab(float* __restrict__ invf) {
  int i = threadIdx.x;  // 64
  invf[i] = 1.0f / (float)pow(10000.0, (double)i / 64.0);
}

// ---------------- f32 -> bf16 bulk convert ----------------
__global__ void k_f2b(const float* __restrict__ in, bf16* __restrict__ out, long n) {
  long i = ((long)blockIdx.x * blockDim.x + threadIdx.x) * 8;
  if (i >= n) return;
  float4 a = *(const float4*)(in + i);
  float4 b = *(const float4*)(in + i + 4);
  bf16x8 o;
  o[0] = (bf16)a.x; o[1] = (bf16)a.y; o[2] = (bf16)a.z; o[3] = (bf16)a.w;
  o[4] = (bf16)b.x; o[5] = (bf16)b.y; o[6] = (bf16)b.z; o[7] = (bf16)b.w;
  *(bf16x8*)(out + i) = o;
}

// ---------------- transpose+convert: f32 [R][C] -> bf16 [C][R] (R,C mult of 64) --------
__global__ __launch_bounds__(256) void k_tconv(const float* __restrict__ in,
                                               bf16* __restrict__ out, int R, int C) {
  __shared__ float t[64][65];
  int nbc = C >> 6;
  long r0 = (long)(blockIdx.x / nbc) * 64, c0 = (long)(blockIdx.x % nbc) * 64;
  int tid = threadIdx.x;
#pragma unroll
  for (int i = 0; i < 4; ++i) {
    int ch = tid + i * 256;
    int r = ch >> 4, c4 = (ch & 15) * 4;
    float4 v = *(const float4*)(in + (r0 + r) * C + c0 + c4);
    t[r][c4] = v.x; t[r][c4 + 1] = v.y; t[r][c4 + 2] = v.z; t[r][c4 + 3] = v.w;
  }
  __syncthreads();
#pragma unroll
  for (int i = 0; i < 2; ++i) {
    int ch = tid + i * 256;
    int c = ch >> 3, r8 = (ch & 7) * 8;
    bf16x8 o;
#pragma unroll
    for (int j = 0; j < 8; ++j) o[j] = (bf16)t[r8 + j][c];
    *(bf16x8*)(out + (c0 + c) * R + r0 + r8) = o;
  }
}

// ------- m97-style GEMM, BK=64 + XOR-swizzled LDS (R6 proven, 841 TF) ------------------
// fuse=1 (QKV): epilogue stages C tile (bias added, bf16) into dead LDS; q/k heads get
// RoPE+RMSNorm -> q_r/k_r, v heads get transpose -> v_t. fuse=0: plain C write.
template <typename OutT>
__global__ __launch_bounds__(256) void k_gemm_bt(
    const bf16* __restrict__ A, const bf16* __restrict__ Bt,
    const float* __restrict__ bias, OutT* __restrict__ C,
    int M, int N, int K, int fuse,
    const float* __restrict__ invf,
    const float* __restrict__ qw, const float* __restrict__ kw,
    bf16* __restrict__ q_r, bf16* __restrict__ k_r, bf16* __restrict__ v_t) {
  __shared__ __align__(16) bf16 lAB[2][128 * 64];   // contiguous: epilogue reuses as [128][128]
  bf16* lA = lAB[0];
  bf16* lB = lAB[1];
  int bid = blockIdx.x;
  if ((gridDim.x & 7) == 0) {  // XCD-aware swizzle (bijective: nwg % 8 == 0)
    int q = gridDim.x >> 3;
    bid = (bid & 7) * q + (bid >> 3);
  }
  int nbn = N >> 7;
  int bm = bid / nbn, bn = bid % nbn;
  const int tid = threadIdx.x, lane = tid & 63, wid = tid >> 6;
  const int wr = wid >> 1, wc = wid & 1;
  const int fr = lane & 15, fq = lane >> 4;
  const long abase = (long)bm * 128 * K, bbase = (long)bn * 128 * K;
  f32x4 acc[4][4] = {};

  for (int k0 = 0; k0 < K; k0 += 64) {
    __syncthreads();
#pragma unroll
    for (int it = 0; it < 4; ++it) {
      int ch = it * 256 + tid;          // 1024 chunks of 16B = [128][64] bf16
      int r = ch >> 3, u = ch & 7;
      load_lds16(A + abase + (long)r * K + k0 + ((u ^ (r & 7)) << 3), &lA[ch * 8]);
    }
#pragma unroll
    for (int it = 0; it < 4; ++it) {
      int ch = it * 256 + tid;
      int r = ch >> 3, u = ch & 7;
      load_lds16(Bt + bbase + (long)r * K + k0 + ((u ^ (r & 7)) << 3), &lB[ch * 8]);
    }
    __syncthreads();
    bf16x8 af[4][2], bf_[4][2];
#pragma unroll
    for (int m = 0; m < 4; ++m) {
      int R = wr * 64 + m * 16 + fr;
#pragma unroll
      for (int kk = 0; kk < 2; ++kk)
        af[m][kk] = *(const bf16x8*)&lA[R * 64 + (((kk * 4 + fq) ^ (R & 7)) << 3)];
    }
#pragma unroll
    for (int n = 0; n < 4; ++n) {
      int R = wc * 64 + n * 16 + fr;
#pragma unroll
      for (int kk = 0; kk < 2; ++kk)
        bf_[n][kk] = *(const bf16x8*)&lB[R * 64 + (((kk * 4 + fq) ^ (R & 7)) << 3)];
    }
#pragma unroll
    for (int m = 0; m < 4; ++m)
#pragma unroll
      for (int n = 0; n < 4; ++n)
#pragma unroll
        for (int kk = 0; kk < 2; ++kk)
          acc[m][n] = __builtin_amdgcn_mfma_f32_16x16x32_bf16(af[m][kk], bf_[n][kk],
                                                              acc[m][n], 0, 0, 0);
  }

  if (!fuse) {
#pragma unroll
    for (int n = 0; n < 4; ++n) {
      int col = bn * 128 + wc * 64 + n * 16 + fr;
      float bv = bias[col];
#pragma unroll
      for (int m = 0; m < 4; ++m) {
        int row0 = bm * 128 + wr * 64 + m * 16 + fq * 4;
#pragma unroll
        for (int r = 0; r < 4; ++r) {
          float v = acc[m][n][r] + bv;
          C[(long)(row0 + r) * N + col] = (OutT)v;
        }
      }
    }
    return;
  }

  // ---------------- fused epilogue (QKV: N=6144, bn 0-15 q / 16-31 k / 32-47 v) --------
  __syncthreads();                       // all waves done with lA/lB fragment reads
  bf16* tile = lAB[0];                   // [128][128] bf16, XOR-swizzled per mode
  const int h = bn & 15;
  const int b = bm >> 4, l0 = (bm & 15) << 7;

  if (bn < 32) {
    // store tile[row][col ^ ((row&7)<<3)]  (row = l-local, col = d)
#pragma unroll
    for (int n = 0; n < 4; ++n) {
      int col = wc * 64 + n * 16 + fr;
      float bv = bias[bn * 128 + col];
#pragma unroll
      for (int m = 0; m < 4; ++m)
#pragma unroll
        for (int r = 0; r < 4; ++r) {
          int row = wr * 64 + m * 16 + fq * 4 + r;
          tile[row * 128 + (col ^ ((row & 7) << 3))] = (bf16)(acc[m][n][r] + bv);
        }
    }
    __syncthreads();
    const float* wv = (bn < 16) ? qw : kw;
    bf16* dst0 = (bn < 16) ? q_r : k_r;
    const int tcol = tid & 15, rgrp = tid >> 4, i8 = tcol * 8;
    const bool lo = i8 < 64;
    float wvv[8], invv[8];
#pragma unroll
    for (int j = 0; j < 8; ++j) wvv[j] = wv[i8 + j];
#pragma unroll
    for (int j = 0; j < 8; ++j) invv[j] = invf[(i8 + j) & 63];
#pragma unroll
    for (int it = 0; it < 8; ++it) {
      int row = it * 16 + rgrp;
      float fl = (float)(l0 + row);
      float cc[8], sn[8];
#pragma unroll
      for (int j = 0; j < 8; ++j) __sincosf(fl * invv[j], &sn[j], &cc[j]);
      bf16x8 xv = *(const bf16x8*)&tile[row * 128 + (i8 ^ ((row & 7) << 3))];
      float v[8], p[8], rr[8];
      float ss = 0.f;
#pragma unroll
      for (int j = 0; j < 8; ++j) v[j] = (float)xv[j];
#pragma unroll
      for (int j = 0; j < 8; ++j) p[j] = __shfl_xor(v[j], 8);  // d <-> d^64
#pragma unroll
      for (int j = 0; j < 8; ++j) {
        rr[j] = lo ? v[j] * cc[j] - p[j] * sn[j] : v[j] * cc[j] + p[j] * sn[j];
        ss += rr[j] * rr[j];
      }
      ss += __shfl_xor(ss, 1);
      ss += __shfl_xor(ss, 2);
      ss += __shfl_xor(ss, 4);
      ss += __shfl_xor(ss, 8);
      float inv = rsqrtf(ss * (1.f / 128.f) + 1e-6f);
      bf16x8 ov;
#pragma unroll
      for (int j = 0; j < 8; ++j) ov[j] = (bf16)(rr[j] * inv * wvv[j]);
      *(bf16x8*)(dst0 + ((long)((b * 16 + h) * 2048 + (l0 + row))) * 128 + i8) = ov;
    }
  } else {
    // v: store transposed tile[col][row ^ ((col&7)<<3)]  (col = d, row = l-local)
#pragma unroll
    for (int n = 0; n < 4; ++n) {
      int col = wc * 64 + n * 16 + fr;
      float bv = bias[bn * 128 + col];
#pragma unroll
      for (int m = 0; m < 4; ++m)
#pragma unroll
        for (int r = 0; r < 4; ++r) {
          int row = wr * 64 + m * 16 + fq * 4 + r;
          tile[col * 128 + (row ^ ((col & 7) << 3))] = (bf16)(acc[m][n][r] + bv);
        }
    }
    __syncthreads();
    // coalesced write: 16 consecutive lanes cover one d-row's 256 B (vs 16B scatter)
    bf16* dstb = v_t + ((long)((b * 16 + h) * 128)) * 2048 + l0;
#pragma unroll
    for (int it = 0; it < 8; ++it) {
      int ch = it * 256 + tid;          // 2048 chunks of 16 B = [128 d][16 chunks]
      int d = ch >> 4, l8 = (ch & 15) * 8;
      bf16x8 vv = *(const bf16x8*)&tile[d * 128 + (l8 ^ ((d & 7) << 3))];
      *(bf16x8*)(dstb + (long)d * 2048 + l8) = vv;
    }
  }
}

// ---------------- flash attention v8: KVBLK=128 (half the barriers/fixed costs) --------
// Same verified structure as R11 (STAGE next -> compute cur -> __syncthreads), head-
// locality swizzle, swapped QK^T 32x32x16, in-reg softmax, shfl-based MKPA. KV tile
// doubled to 128: 16 loop iterations instead of 32; PV processed in two kv-halves
// reusing pa[4] to cap VGPR. LDS 2x(32KB K + 32KB V) = 128 KB.
__global__ __launch_bounds__(512, 1) void k_attn(
    const bf16* __restrict__ q_r, const bf16* __restrict__ k_r,
    const bf16* __restrict__ v_t, const unsigned char* __restrict__ amask,
    bf16* __restrict__ attno) {
  __shared__ __align__(16) bf16 lK[2][128 * 128];  // [kv][dh], XOR-swizzled (16B chunks)
  __shared__ __align__(16) bf16 lV[2][128 * 128];  // [dh][kv], XOR-swizzled
  __shared__ int sAny;
  const int tid = threadIdx.x, lane = tid & 63, w = tid >> 6;
  const int hi = lane >> 5, q31 = lane & 31;
  const int bh = blockIdx.x & 31, qt = blockIdx.x >> 5;
  const int b = bh >> 4, h = bh & 15;
  const long hbase = (long)bh * 2048 * 128;
  const int q0 = qt * 256 + w * 32;
  const unsigned char* mb = amask + b * 2048;

  if (tid == 0) sAny = 0;
  __syncthreads();
  {
    unsigned mv = *(const unsigned*)(mb + tid * 4);
    if (mv) sAny = 1;
  }

  // Q fragments (B-operand of 32x32x16): qf[ksl][j] = Q[q0+q31][ksl*16 + hi*8 + j]
  bf16x8 qf[8];
#pragma unroll
  for (int ksl = 0; ksl < 8; ++ksl)
    qf[ksl] = *(const bf16x8*)(q_r + hbase + (long)(q0 + q31) * 128 + ksl * 16 + hi * 8);

  f32x16 o[4] = {};          // o[dt][reg]: O[q=crow(reg,hi)][d=dt*32+q31]
  float m_run = -1e30f, l_run = 0.f;
  const float SC2 = 0.08838834764831845f * 1.4426950408889634f;  // 1/sqrt(128) * log2(e)
  const float L2E = 1.4426950408889634f;

  // stage K tile [128 kv][128 dh] and V tile [128 dh][128 kv] (16 chunks/row each)
#define STAGE(buf, kv0)                                                              \
  {                                                                                  \
    _Pragma("unroll") for (int it = 0; it < 4; ++it) {                               \
      int g = it * 512 + w * 64 + lane;                                              \
      int r = g >> 4, u = g & 15;                                                    \
      load_lds16(k_r + hbase + (long)((kv0) + r) * 128 + ((u ^ (r & 7)) << 3),       \
                 &lK[buf][(it * 512 + w * 64) * 8]);                                 \
    }                                                                                \
    _Pragma("unroll") for (int it = 0; it < 4; ++it) {                               \
      int g = it * 512 + w * 64 + lane;                                              \
      int r = g >> 4, u = g & 15;                                                    \
      load_lds16(v_t + hbase + (long)r * 2048 + (kv0) + ((u ^ (r & 7)) << 3),        \
                 &lV[buf][(it * 512 + w * 64) * 8]);                                 \
    }                                                                                \
  }

  STAGE(0, 0);
  __syncthreads();
  const bool maskAny = sAny != 0;
  int cur = 0;
  for (int t = 0; t < 16; ++t) {
    const int kv0 = t << 7;
    if (t < 15) STAGE(cur ^ 1, kv0 + 128);

    // ---- S^T = K Q^T : st0..st3 = kv {0..31,32..63,64..95,96..127}; col q = q31 ----
    f32x16 st0 = {}, st1 = {}, st2 = {}, st3 = {};
#pragma unroll
    for (int ksl = 0; ksl < 8; ++ksl) {
      const int u = ksl * 2 + hi;
      bf16x8 kf0 = *(const bf16x8*)&lK[cur][q31 * 128 + ((u ^ (q31 & 7)) << 3)];
      bf16x8 kf1 = *(const bf16x8*)&lK[cur][(32 + q31) * 128 + ((u ^ (q31 & 7)) << 3)];
      bf16x8 kf2 = *(const bf16x8*)&lK[cur][(64 + q31) * 128 + ((u ^ (q31 & 7)) << 3)];
      bf16x8 kf3 = *(const bf16x8*)&lK[cur][(96 + q31) * 128 + ((u ^ (q31 & 7)) << 3)];
      st0 = __builtin_amdgcn_mfma_f32_32x32x16_bf16(kf0, qf[ksl], st0, 0, 0, 0);
      st1 = __builtin_amdgcn_mfma_f32_32x32x16_bf16(kf1, qf[ksl], st1, 0, 0, 0);
      st2 = __builtin_amdgcn_mfma_f32_32x32x16_bf16(kf2, qf[ksl], st2, 0, 0, 0);
      st3 = __builtin_amdgcn_mfma_f32_32x32x16_bf16(kf3, qf[ksl], st3, 0, 0, 0);
    }

#pragma unroll
    for (int i = 0; i < 16; ++i) {
      st0[i] *= SC2; st1[i] *= SC2; st2[i] *= SC2; st3[i] *= SC2;
    }
    if (maskAny) {
#pragma unroll
      for (int i = 0; i < 16; ++i) {
        int c = (i & 3) + 8 * (i >> 2) + 4 * hi;
        if (mb[kv0 + c]) st0[i] += L2E;
        if (mb[kv0 + 32 + c]) st1[i] += L2E;
        if (mb[kv0 + 64 + c]) st2[i] += L2E;
        if (mb[kv0 + 96 + c]) st3[i] += L2E;
      }
    }

    // ---- in-register row max ----
    float tm = st0[0];
#pragma unroll
    for (int i = 1; i < 16; ++i) tm = fmaxf(tm, st0[i]);
#pragma unroll
    for (int i = 0; i < 16; ++i) tm = fmaxf(tm, st1[i]);
#pragma unroll
    for (int i = 0; i < 16; ++i) tm = fmaxf(tm, st2[i]);
#pragma unroll
    for (int i = 0; i < 16; ++i) tm = fmaxf(tm, st3[i]);
    tm = fmaxf(tm, __shfl_xor(tm, 32));

    if (!__all(tm <= m_run + 8.f)) {  // T13 defer-max, THR=8 (factor 256 headroom)
      float mn = fmaxf(m_run, tm);
      float corr = exp2f(m_run - mn);
      m_run = mn;
      l_run *= corr;
#pragma unroll
      for (int i = 0; i < 16; ++i) {
        float cr = __shfl(corr, (i & 3) + 8 * (i >> 2) + 4 * hi);
#pragma unroll
        for (int dt = 0; dt < 4; ++dt) o[dt][i] *= cr;
      }
    }

    // ---- exp + row sum ----
    float rs = 0.f;
#pragma unroll
    for (int i = 0; i < 16; ++i) { st0[i] = exp2f(st0[i] - m_run); rs += st0[i]; }
#pragma unroll
    for (int i = 0; i < 16; ++i) { st1[i] = exp2f(st1[i] - m_run); rs += st1[i]; }
#pragma unroll
    for (int i = 0; i < 16; ++i) { st2[i] = exp2f(st2[i] - m_run); rs += st2[i]; }
#pragma unroll
    for (int i = 0; i < 16; ++i) { st3[i] = exp2f(st3[i] - m_run); rs += st3[i]; }
    rs += __shfl_xor(rs, 32);
    l_run += rs;

    // ---- P -> bf16 PV A-frags via packed half-swap (proven shfl_xor path) ----
    union UU { bf16x4 v; uint2 u; };
    union U8 { bf16x8 v; uint4 u; };
    bf16x8 pa[4];
#define MKPA(pidx, STX, bb)                                                          \
  {                                                                                  \
    UU plo, phi;                                                                     \
    plo.v = (bf16x4){(bf16)STX[bb], (bf16)STX[(bb) + 1], (bf16)STX[(bb) + 2],        \
                     (bf16)STX[(bb) + 3]};                                           \
    phi.v = (bf16x4){(bf16)STX[(bb) + 4], (bf16)STX[(bb) + 5], (bf16)STX[(bb) + 6],  \
                     (bf16)STX[(bb) + 7]};                                           \
    unsigned sx = hi ? plo.u.x : phi.u.x, sy = hi ? plo.u.y : phi.u.y;               \
    unsigned rx = (unsigned)__shfl_xor((int)sx, 32), ry = (unsigned)__shfl_xor((int)sy, 32); \
    U8 f;                                                                            \
    f.u.x = hi ? rx : plo.u.x; f.u.y = hi ? ry : plo.u.y;                            \
    f.u.z = hi ? phi.u.x : rx; f.u.w = hi ? phi.u.y : ry;                            \
    pa[pidx] = f.v;                                                                  \
  }
    // ---- O += P V, kv-half A (0..63) ----
    MKPA(0, st0, 0) MKPA(1, st0, 8) MKPA(2, st1, 0) MKPA(3, st1, 8)
#pragma unroll
    for (int dt = 0; dt < 4; ++dt) {
      const int dr = dt * 32 + q31;
#pragma unroll
      for (int ks = 0; ks < 4; ++ks) {
        const int u = ks * 2 + hi;
        bf16x8 vb = *(const bf16x8*)&lV[cur][dr * 128 + ((u ^ (dr & 7)) << 3)];
        o[dt] = __builtin_amdgcn_mfma_f32_32x32x16_bf16(pa[ks], vb, o[dt], 0, 0, 0);
      }
    }
    // ---- O += P V, kv-half B (64..127) ----
    MKPA(0, st2, 0) MKPA(1, st2, 8) MKPA(2, st3, 0) MKPA(3, st3, 8)
#pragma unroll
    for (int dt = 0; dt < 4; ++dt) {
      const int dr = dt * 32 + q31;
#pragma unroll
      for (int ks = 0; ks < 4; ++ks) {
        const int u = (ks + 4) * 2 + hi;
        bf16x8 vb = *(const bf16x8*)&lV[cur][dr * 128 + ((u ^ (dr & 7)) << 3)];
        o[dt] = __builtin_amdgcn_mfma_f32_32x32x16_bf16(pa[ks], vb, o[dt], 0, 0, 0);
      }
    }
#undef MKPA

    __syncthreads();  // drains this iter's STAGE vmcnt; all waves done reading cur
    cur ^= 1;
  }
#undef STAGE

  // ---- epilogue: 1/l via shfl, padding-row zero, store [B,L,H*DH] bf16 ----
  float invl = 1.f / l_run;
#pragma unroll
  for (int i = 0; i < 16; ++i) {
    int q = (i & 3) + 8 * (i >> 2) + 4 * hi;
    int qrow = q0 + q;
    float inv = __shfl(invl, q);
    float zm = inv;
    if (maskAny) { if (mb[qrow]) zm = 0.f; }
#pragma unroll
    for (int dt = 0; dt < 4; ++dt)
      attno[(long)(b * 2048 + qrow) * 2048 + h * 128 + dt * 32 + q31] = (bf16)(o[dt][i] * zm);
  }
}

extern "C" void kernel_launch(void* const* d_in, const int* in_sizes, int n_in,
                              void* d_out, int out_size, void* d_ws, size_t ws_size,
                              hipStream_t stream) {
  const float* x = (const float*)d_in[0];
  const unsigned char* amask = (const unsigned char*)d_in[1];
  const float* Wqkv = (const float*)d_in[2];
  const float* bqkv = (const float*)d_in[3];
  const float* Wout = (const float*)d_in[4];
  const float* bout = (const float*)d_in[5];
  const float* qw = (const float*)d_in[6];
  const float* kw = (const float*)d_in[7];
  float* out = (float*)d_out;
  char* ws = (char*)d_ws;

  bf16* xb   = (bf16*)(ws);                         // 16 MB (reused as attnout later)
  bf16* wqT  = (bf16*)(ws + 16777216);              // 24 MB  Wqkv^T [6144][2048]
  bf16* woT  = (bf16*)(ws + 41943040);              // 8 MB   Wout^T [2048][2048]
  bf16* q_r  = (bf16*)(ws + 100663296);             // 16 MB  [B*H,L,DH]
  bf16* k_r  = (bf16*)(ws + 117440512);             // 16 MB
  bf16* v_t  = (bf16*)(ws + 134217728);             // 16 MB  [B*H,DH,L]
  float* invf = (float*)(ws + 150994944);           // 256 B
  bf16* attno = xb;  // alias: x_bf16 dead after QKV GEMM

  k_tab<<<1, 64, 0, stream>>>(invf);
  k_f2b<<<4096, 256, 0, stream>>>(x, xb, 8388608L);
  k_tconv<<<32 * 96, 256, 0, stream>>>(Wqkv, wqT, 2048, 6144);
  k_tconv<<<32 * 32, 256, 0, stream>>>(Wout, woT, 2048, 2048);
  k_gemm_bt<bf16><<<32 * 48, 256, 0, stream>>>(xb, wqT, bqkv, (bf16*)nullptr,
                                               4096, 6144, 2048, 1,
                                               invf, qw, kw, q_r, k_r, v_t);
  k_attn<<<256, 512, 0, stream>>>(q_r, k_r, v_t, amask, attno);
  k_gemm_bt<float><<<32 * 16, 256, 0, stream>>>(attno, woT, bout, out,
                                                4096, 2048, 2048, 0,
                                                nullptr, nullptr, nullptr,
                                                nullptr, nullptr, nullptr);
}

// Round 15
// 304.224 us; speedup vs baseline: 1.0194x; 1.0146x over previous
//
#include <hip/hip_runtime.h>
#include <hip/hip_bf16.h>

typedef __bf16 bf16;
using bf16x8 = __attribute__((ext_vector_type(8))) __bf16;
using bf16x4 = __attribute__((ext_vector_type(4))) __bf16;
using f32x4  = __attribute__((ext_vector_type(4))) float;
using f32x16 = __attribute__((ext_vector_type(16))) float;

#define DEV __device__ __forceinline__

DEV void load_lds16(const void* g, void* l) {
  __builtin_amdgcn_global_load_lds(
      (const __attribute__((address_space(1))) void*)g,
      (__attribute__((address_space(3))) void*)l, 16, 0, 0);
}

// ---------------- merged preprocessing: f2b(x) + tconv(Wqkv) + tconv(Wout) + invf ------
__global__ __launch_bounds__(256) void k_prep(
    const float* __restrict__ x, bf16* __restrict__ xb,
    const float* __restrict__ Wq, bf16* __restrict__ wqT,
    const float* __restrict__ Wo, bf16* __restrict__ woT,
    float* __restrict__ invf) {
  __shared__ float t[64][65];
  int bid = blockIdx.x;
  int tid = threadIdx.x;
  if (bid < 4096) {                      // f32 -> bf16 convert of x
    long i = ((long)bid * 256 + tid) * 8;
    float4 a = *(const float4*)(x + i);
    float4 b = *(const float4*)(x + i + 4);
    bf16x8 o;
    o[0] = (bf16)a.x; o[1] = (bf16)a.y; o[2] = (bf16)a.z; o[3] = (bf16)a.w;
    o[4] = (bf16)b.x; o[5] = (bf16)b.y; o[6] = (bf16)b.z; o[7] = (bf16)b.w;
    *(bf16x8*)(xb + i) = o;
    return;
  }
  if (bid >= 8192) {                     // RoPE inverse-frequency table
    if (tid < 64) invf[tid] = 1.0f / (float)pow(10000.0, (double)tid / 64.0);
    return;
  }
  const float* in;
  bf16* out;
  int R, C, rb;
  if (bid < 7168) { in = Wq; out = wqT; R = 2048; C = 6144; rb = bid - 4096; }
  else            { in = Wo; out = woT; R = 2048; C = 2048; rb = bid - 7168; }
  int nbc = C >> 6;
  long r0 = (long)(rb / nbc) * 64, c0 = (long)(rb % nbc) * 64;
#pragma unroll
  for (int i = 0; i < 4; ++i) {
    int ch = tid + i * 256;
    int r = ch >> 4, c4 = (ch & 15) * 4;
    float4 v = *(const float4*)(in + (r0 + r) * C + c0 + c4);
    t[r][c4] = v.x; t[r][c4 + 1] = v.y; t[r][c4 + 2] = v.z; t[r][c4 + 3] = v.w;
  }
  __syncthreads();
#pragma unroll
  for (int i = 0; i < 2; ++i) {
    int ch = tid + i * 256;
    int c = ch >> 3, r8 = (ch & 7) * 8;
    bf16x8 o;
#pragma unroll
    for (int j = 0; j < 8; ++j) o[j] = (bf16)t[r8 + j][c];
    *(bf16x8*)(out + (c0 + c) * R + r0 + r8) = o;
  }
}

// ------- m97-style GEMM, BK=64 + XOR-swizzled LDS (R6 proven, 841 TF) ------------------
// fuse=1 (QKV): epilogue stages C tile (bias added, bf16) into dead LDS; q/k heads get
// RoPE+RMSNorm -> q_r/k_r, v heads get transpose -> v_t. fuse=0: plain C write.
template <typename OutT>
__global__ __launch_bounds__(256) void k_gemm_bt(
    const bf16* __restrict__ A, const bf16* __restrict__ Bt,
    const float* __restrict__ bias, OutT* __restrict__ C,
    int M, int N, int K, int fuse,
    const float* __restrict__ invf,
    const float* __restrict__ qw, const float* __restrict__ kw,
    bf16* __restrict__ q_r, bf16* __restrict__ k_r, bf16* __restrict__ v_t) {
  __shared__ __align__(16) bf16 lAB[2][128 * 64];   // contiguous: epilogue reuses as [128][128]
  bf16* lA = lAB[0];
  bf16* lB = lAB[1];
  int bid = blockIdx.x;
  if ((gridDim.x & 7) == 0) {  // XCD-aware swizzle (bijective: nwg % 8 == 0)
    int q = gridDim.x >> 3;
    bid = (bid & 7) * q + (bid >> 3);
  }
  int nbn = N >> 7;
  int bm = bid / nbn, bn = bid % nbn;
  const int tid = threadIdx.x, lane = tid & 63, wid = tid >> 6;
  const int wr = wid >> 1, wc = wid & 1;
  const int fr = lane & 15, fq = lane >> 4;
  const long abase = (long)bm * 128 * K, bbase = (long)bn * 128 * K;
  f32x4 acc[4][4] = {};

  for (int k0 = 0; k0 < K; k0 += 64) {
    __syncthreads();
#pragma unroll
    for (int it = 0; it < 4; ++it) {
      int ch = it * 256 + tid;          // 1024 chunks of 16B = [128][64] bf16
      int r = ch >> 3, u = ch & 7;
      load_lds16(A + abase + (long)r * K + k0 + ((u ^ (r & 7)) << 3), &lA[ch * 8]);
    }
#pragma unroll
    for (int it = 0; it < 4; ++it) {
      int ch = it * 256 + tid;
      int r = ch >> 3, u = ch & 7;
      load_lds16(Bt + bbase + (long)r * K + k0 + ((u ^ (r & 7)) << 3), &lB[ch * 8]);
    }
    __syncthreads();
    bf16x8 af[4][2], bf_[4][2];
#pragma unroll
    for (int m = 0; m < 4; ++m) {
      int R = wr * 64 + m * 16 + fr;
#pragma unroll
      for (int kk = 0; kk < 2; ++kk)
        af[m][kk] = *(const bf16x8*)&lA[R * 64 + (((kk * 4 + fq) ^ (R & 7)) << 3)];
    }
#pragma unroll
    for (int n = 0; n < 4; ++n) {
      int R = wc * 64 + n * 16 + fr;
#pragma unroll
      for (int kk = 0; kk < 2; ++kk)
        bf_[n][kk] = *(const bf16x8*)&lB[R * 64 + (((kk * 4 + fq) ^ (R & 7)) << 3)];
    }
#pragma unroll
    for (int m = 0; m < 4; ++m)
#pragma unroll
      for (int n = 0; n < 4; ++n)
#pragma unroll
        for (int kk = 0; kk < 2; ++kk)
          acc[m][n] = __builtin_amdgcn_mfma_f32_16x16x32_bf16(af[m][kk], bf_[n][kk],
                                                              acc[m][n], 0, 0, 0);
  }

  if (!fuse) {
#pragma unroll
    for (int n = 0; n < 4; ++n) {
      int col = bn * 128 + wc * 64 + n * 16 + fr;
      float bv = bias[col];
#pragma unroll
      for (int m = 0; m < 4; ++m) {
        int row0 = bm * 128 + wr * 64 + m * 16 + fq * 4;
#pragma unroll
        for (int r = 0; r < 4; ++r) {
          float v = acc[m][n][r] + bv;
          C[(long)(row0 + r) * N + col] = (OutT)v;
        }
      }
    }
    return;
  }

  // ---------------- fused epilogue (QKV: N=6144, bn 0-15 q / 16-31 k / 32-47 v) --------
  __syncthreads();                       // all waves done with lA/lB fragment reads
  bf16* tile = lAB[0];                   // [128][128] bf16, XOR-swizzled per mode
  const int h = bn & 15;
  const int b = bm >> 4, l0 = (bm & 15) << 7;

  if (bn < 32) {
    // store tile[row][col ^ ((row&7)<<3)]  (row = l-local, col = d)
#pragma unroll
    for (int n = 0; n < 4; ++n) {
      int col = wc * 64 + n * 16 + fr;
      float bv = bias[bn * 128 + col];
#pragma unroll
      for (int m = 0; m < 4; ++m)
#pragma unroll
        for (int r = 0; r < 4; ++r) {
          int row = wr * 64 + m * 16 + fq * 4 + r;
          tile[row * 128 + (col ^ ((row & 7) << 3))] = (bf16)(acc[m][n][r] + bv);
        }
    }
    __syncthreads();
    const float* wv = (bn < 16) ? qw : kw;
    bf16* dst0 = (bn < 16) ? q_r : k_r;
    const int tcol = tid & 15, rgrp = tid >> 4, i8 = tcol * 8;
    const bool lo = i8 < 64;
    float wvv[8], invv[8];
#pragma unroll
    for (int j = 0; j < 8; ++j) wvv[j] = wv[i8 + j];
#pragma unroll
    for (int j = 0; j < 8; ++j) invv[j] = invf[(i8 + j) & 63];
#pragma unroll
    for (int it = 0; it < 8; ++it) {
      int row = it * 16 + rgrp;
      float fl = (float)(l0 + row);
      float cc[8], sn[8];
#pragma unroll
      for (int j = 0; j < 8; ++j) __sincosf(fl * invv[j], &sn[j], &cc[j]);
      bf16x8 xv = *(const bf16x8*)&tile[row * 128 + (i8 ^ ((row & 7) << 3))];
      float v[8], p[8], rr[8];
      float ss = 0.f;
#pragma unroll
      for (int j = 0; j < 8; ++j) v[j] = (float)xv[j];
#pragma unroll
      for (int j = 0; j < 8; ++j) p[j] = __shfl_xor(v[j], 8);  // d <-> d^64
#pragma unroll
      for (int j = 0; j < 8; ++j) {
        rr[j] = lo ? v[j] * cc[j] - p[j] * sn[j] : v[j] * cc[j] + p[j] * sn[j];
        ss += rr[j] * rr[j];
      }
      ss += __shfl_xor(ss, 1);
      ss += __shfl_xor(ss, 2);
      ss += __shfl_xor(ss, 4);
      ss += __shfl_xor(ss, 8);
      float inv = rsqrtf(ss * (1.f / 128.f) + 1e-6f);
      bf16x8 ov;
#pragma unroll
      for (int j = 0; j < 8; ++j) ov[j] = (bf16)(rr[j] * inv * wvv[j]);
      *(bf16x8*)(dst0 + ((long)((b * 16 + h) * 2048 + (l0 + row))) * 128 + i8) = ov;
    }
  } else {
    // v: store transposed tile[col][row ^ ((col&7)<<3)]  (col = d, row = l-local)
#pragma unroll
    for (int n = 0; n < 4; ++n) {
      int col = wc * 64 + n * 16 + fr;
      float bv = bias[bn * 128 + col];
#pragma unroll
      for (int m = 0; m < 4; ++m)
#pragma unroll
        for (int r = 0; r < 4; ++r) {
          int row = wr * 64 + m * 16 + fq * 4 + r;
          tile[col * 128 + (row ^ ((col & 7) << 3))] = (bf16)(acc[m][n][r] + bv);
        }
    }
    __syncthreads();
    // coalesced write: 16 consecutive lanes cover one d-row's 256 B (vs 16B scatter)
    bf16* dstb = v_t + ((long)((b * 16 + h) * 128)) * 2048 + l0;
#pragma unroll
    for (int it = 0; it < 8; ++it) {
      int ch = it * 256 + tid;          // 2048 chunks of 16 B = [128 d][16 chunks]
      int d = ch >> 4, l8 = (ch & 15) * 8;
      bf16x8 vv = *(const bf16x8*)&tile[d * 128 + (l8 ^ ((d & 7) << 3))];
      *(bf16x8*)(dstb + (long)d * 2048 + l8) = vv;
    }
  }
}

// ---------------- flash attention v9: T15 double-pipeline (KVBLK=64) -------------------
// 2 K-buffers + 3 V-buffers (80 KB): all staging issues at iter top (hidden under
// compute); QK(t+1) emitted BEFORE softmax(t) so the MFMA pipe overlaps the softmax
// VALU chain (T15 mechanism). Hazard audit: every buffer's last read precedes the
// barrier that precedes its overwrite (prologue barrier protects kbuf0).
__global__ __launch_bounds__(512, 1) void k_attn(
    const bf16* __restrict__ q_r, const bf16* __restrict__ k_r,
    const bf16* __restrict__ v_t, const unsigned char* __restrict__ amask,
    bf16* __restrict__ attno) {
  __shared__ __align__(16) bf16 lK[2][64 * 128];   // [kv][dh], XOR-swizzled (16B chunks)
  __shared__ __align__(16) bf16 lV[3][128 * 64];   // [dh][kv], XOR-swizzled
  __shared__ int sAny;
  const int tid = threadIdx.x, lane = tid & 63, w = tid >> 6;
  const int hi = lane >> 5, q31 = lane & 31;
  const int bh = blockIdx.x & 31, qt = blockIdx.x >> 5;   // head-locality swizzle
  const int b = bh >> 4, h = bh & 15;
  const long hbase = (long)bh * 2048 * 128;
  const int q0 = qt * 256 + w * 32;
  const unsigned char* mb = amask + b * 2048;

  if (tid == 0) sAny = 0;
  __syncthreads();
  {
    unsigned mv = *(const unsigned*)(mb + tid * 4);
    if (mv) sAny = 1;
  }

  // Q fragments (B-operand of 32x32x16): qf[ksl][j] = Q[q0+q31][ksl*16 + hi*8 + j]
  bf16x8 qf[8];
#pragma unroll
  for (int ksl = 0; ksl < 8; ++ksl)
    qf[ksl] = *(const bf16x8*)(q_r + hbase + (long)(q0 + q31) * 128 + ksl * 16 + hi * 8);

  f32x16 o[4] = {};          // o[dt][reg]: O[q=crow(reg,hi)][d=dt*32+q31]
  float m_run = -1e30f, l_run = 0.f;
  const float SC2 = 0.08838834764831845f * 1.4426950408889634f;  // 1/sqrt(128) * log2(e)
  const float L2E = 1.4426950408889634f;

#define STAGE_K(buf, kv0)                                                            \
  {                                                                                  \
    _Pragma("unroll") for (int it = 0; it < 2; ++it) {                               \
      int g = it * 512 + w * 64 + lane;                                              \
      int r = g >> 4, u = g & 15;                                                    \
      load_lds16(k_r + hbase + (long)((kv0) + r) * 128 + ((u ^ (r & 7)) << 3),       \
                 &lK[buf][(it * 512 + w * 64) * 8]);                                 \
    }                                                                                \
  }
#define STAGE_V(buf, kv0)                                                            \
  {                                                                                  \
    _Pragma("unroll") for (int it = 0; it < 2; ++it) {                               \
      int g = it * 512 + w * 64 + lane;                                              \
      int r = g >> 3, u = g & 7;                                                     \
      load_lds16(v_t + hbase + (long)r * 2048 + (kv0) + ((u ^ (r & 7)) << 3),        \
                 &lV[buf][(it * 512 + w * 64) * 8]);                                 \
    }                                                                                \
  }

  STAGE_K(0, 0) STAGE_V(0, 0) STAGE_K(1, 64) STAGE_V(1, 64)
  __syncthreads();           // tiles 0 and 1 resident
  const bool maskAny = sAny != 0;

  // prologue: S(0) raw scores from lK[0]
  f32x16 st0 = {}, st1 = {};
#pragma unroll
  for (int ksl = 0; ksl < 8; ++ksl) {
    const int u = ksl * 2 + hi;
    bf16x8 kf0 = *(const bf16x8*)&lK[0][q31 * 128 + ((u ^ (q31 & 7)) << 3)];
    bf16x8 kf1 = *(const bf16x8*)&lK[0][(32 + q31) * 128 + ((u ^ (q31 & 7)) << 3)];
    st0 = __builtin_amdgcn_mfma_f32_32x32x16_bf16(kf0, qf[ksl], st0, 0, 0, 0);
    st1 = __builtin_amdgcn_mfma_f32_32x32x16_bf16(kf1, qf[ksl], st1, 0, 0, 0);
  }
  __syncthreads();           // all waves done reading kbuf0 before iter-0 overwrites it

  for (int t = 0; t < 32; ++t) {
    const int kv0 = t << 6;
    if (t + 2 < 32) {
      STAGE_K(t & 1, kv0 + 128)            // kbuf[(t+2)&1] == kbuf[t&1], free since iter t-1
      STAGE_V((t + 2) % 3, kv0 + 128)      // vbuf free since PV(t-1)
    }

    // ---- next-tile QK (independent of softmax below -> MFMA overlaps VALU) ----
    f32x16 sn0 = {}, sn1 = {};
    if (t < 31) {
      const bf16* kb = lK[(t + 1) & 1];
#pragma unroll
      for (int ksl = 0; ksl < 8; ++ksl) {
        const int u = ksl * 2 + hi;
        bf16x8 kf0 = *(const bf16x8*)&kb[q31 * 128 + ((u ^ (q31 & 7)) << 3)];
        bf16x8 kf1 = *(const bf16x8*)&kb[(32 + q31) * 128 + ((u ^ (q31 & 7)) << 3)];
        sn0 = __builtin_amdgcn_mfma_f32_32x32x16_bf16(kf0, qf[ksl], sn0, 0, 0, 0);
        sn1 = __builtin_amdgcn_mfma_f32_32x32x16_bf16(kf1, qf[ksl], sn1, 0, 0, 0);
      }
    }

    // ---- softmax on S(t) = st0,st1 ----
#pragma unroll
    for (int i = 0; i < 16; ++i) { st0[i] *= SC2; st1[i] *= SC2; }
    if (maskAny) {
#pragma unroll
      for (int i = 0; i < 16; ++i) {
        int c = (i & 3) + 8 * (i >> 2) + 4 * hi;
        if (mb[kv0 + c]) st0[i] += L2E;
        if (mb[kv0 + 32 + c]) st1[i] += L2E;
      }
    }
    float tm = st0[0];
#pragma unroll
    for (int i = 1; i < 16; ++i) tm = fmaxf(tm, st0[i]);
#pragma unroll
    for (int i = 0; i < 16; ++i) tm = fmaxf(tm, st1[i]);
    tm = fmaxf(tm, __shfl_xor(tm, 32));

    if (!__all(tm <= m_run + 8.f)) {  // T13 defer-max, THR=8
      float mn = fmaxf(m_run, tm);
      float corr = exp2f(m_run - mn);
      m_run = mn;
      l_run *= corr;
#pragma unroll
      for (int i = 0; i < 16; ++i) {
        float cr = __shfl(corr, (i & 3) + 8 * (i >> 2) + 4 * hi);
#pragma unroll
        for (int dt = 0; dt < 4; ++dt) o[dt][i] *= cr;
      }
    }

    float rs = 0.f;
#pragma unroll
    for (int i = 0; i < 16; ++i) { st0[i] = exp2f(st0[i] - m_run); rs += st0[i]; }
#pragma unroll
    for (int i = 0; i < 16; ++i) { st1[i] = exp2f(st1[i] - m_run); rs += st1[i]; }
    rs += __shfl_xor(rs, 32);
    l_run += rs;

    // ---- P -> bf16 PV A-frags via packed half-swap (proven shfl_xor path) ----
    union UU { bf16x4 v; uint2 u; };
    union U8 { bf16x8 v; uint4 u; };
    bf16x8 pa[4];
#define MKPA(pidx, STX, bb)                                                          \
  {                                                                                  \
    UU plo, phi;                                                                     \
    plo.v = (bf16x4){(bf16)STX[bb], (bf16)STX[(bb) + 1], (bf16)STX[(bb) + 2],        \
                     (bf16)STX[(bb) + 3]};                                           \
    phi.v = (bf16x4){(bf16)STX[(bb) + 4], (bf16)STX[(bb) + 5], (bf16)STX[(bb) + 6],  \
                     (bf16)STX[(bb) + 7]};                                           \
    unsigned sx = hi ? plo.u.x : phi.u.x, sy = hi ? plo.u.y : phi.u.y;               \
    unsigned rx = (unsigned)__shfl_xor((int)sx, 32), ry = (unsigned)__shfl_xor((int)sy, 32); \
    U8 f;                                                                            \
    f.u.x = hi ? rx : plo.u.x; f.u.y = hi ? ry : plo.u.y;                            \
    f.u.z = hi ? phi.u.x : rx; f.u.w = hi ? phi.u.y : ry;                            \
    pa[pidx] = f.v;                                                                  \
  }
    MKPA(0, st0, 0) MKPA(1, st0, 8) MKPA(2, st1, 0) MKPA(3, st1, 8)
#undef MKPA

    // ---- O += P V from vbuf[t % 3] ----
    const bf16* vb3 = lV[t % 3];
#pragma unroll
    for (int dt = 0; dt < 4; ++dt) {
      const int dr = dt * 32 + q31;
#pragma unroll
      for (int ks = 0; ks < 4; ++ks) {
        const int u = ks * 2 + hi;
        bf16x8 vb = *(const bf16x8*)&vb3[dr * 64 + ((u ^ (dr & 7)) << 3)];
        o[dt] = __builtin_amdgcn_mfma_f32_32x32x16_bf16(pa[ks], vb, o[dt], 0, 0, 0);
      }
    }

    __syncthreads();   // drains this iter's stages; all waves done with read buffers
    st0 = sn0;
    st1 = sn1;
  }
#undef STAGE_K
#undef STAGE_V

  // ---- epilogue: 1/l via shfl, padding-row zero, store [B,L,H*DH] bf16 ----
  float invl = 1.f / l_run;
#pragma unroll
  for (int i = 0; i < 16; ++i) {
    int q = (i & 3) + 8 * (i >> 2) + 4 * hi;
    int qrow = q0 + q;
    float inv = __shfl(invl, q);
    float zm = inv;
    if (maskAny) { if (mb[qrow]) zm = 0.f; }
#pragma unroll
    for (int dt = 0; dt < 4; ++dt)
      attno[(long)(b * 2048 + qrow) * 2048 + h * 128 + dt * 32 + q31] = (bf16)(o[dt][i] * zm);
  }
}

extern "C" void kernel_launch(void* const* d_in, const int* in_sizes, int n_in,
                              void* d_out, int out_size, void* d_ws, size_t ws_size,
                              hipStream_t stream) {
  const float* x = (const float*)d_in[0];
  const unsigned char* amask = (const unsigned char*)d_in[1];
  const float* Wqkv = (const float*)d_in[2];
  const float* bqkv = (const float*)d_in[3];
  const float* Wout = (const float*)d_in[4];
  const float* bout = (const float*)d_in[5];
  const float* qw = (const float*)d_in[6];
  const float* kw = (const float*)d_in[7];
  float* out = (float*)d_out;
  char* ws = (char*)d_ws;

  bf16* xb   = (bf16*)(ws);                         // 16 MB (reused as attnout later)
  bf16* wqT  = (bf16*)(ws + 16777216);              // 24 MB  Wqkv^T [6144][2048]
  bf16* woT  = (bf16*)(ws + 41943040);              // 8 MB   Wout^T [2048][2048]
  bf16* q_r  = (bf16*)(ws + 100663296);             // 16 MB  [B*H,L,DH]
  bf16* k_r  = (bf16*)(ws + 117440512);             // 16 MB
  bf16* v_t  = (bf16*)(ws + 134217728);             // 16 MB  [B*H,DH,L]
  float* invf = (float*)(ws + 150994944);           // 256 B
  bf16* attno = xb;  // alias: x_bf16 dead after QKV GEMM

  k_prep<<<8193, 256, 0, stream>>>(x, xb, Wqkv, wqT, Wout, woT, invf);
  k_gemm_bt<bf16><<<32 * 48, 256, 0, stream>>>(xb, wqT, bqkv, (bf16*)nullptr,
                                               4096, 6144, 2048, 1,
                                               invf, qw, kw, q_r, k_r, v_t);
  k_attn<<<256, 512, 0, stream>>>(q_r, k_r, v_t, amask, attno);
  k_gemm_bt<float><<<32 * 16, 256, 0, stream>>>(attno, woT, bout, out,
                                                4096, 2048, 2048, 0,
                                                nullptr, nullptr, nullptr,
                                                nullptr, nullptr, nullptr);
}

// Round 16
// 289.316 us; speedup vs baseline: 1.0719x; 1.0515x over previous
//
#include <hip/hip_runtime.h>
#include <hip/hip_bf16.h>

typedef __bf16 bf16;
using bf16x8 = __attribute__((ext_vector_type(8))) __bf16;
using bf16x4 = __attribute__((ext_vector_type(4))) __bf16;
using f32x4  = __attribute__((ext_vector_type(4))) float;
using f32x16 = __attribute__((ext_vector_type(16))) float;

#define DEV __device__ __forceinline__

DEV void load_lds16(const void* g, void* l) {
  __builtin_amdgcn_global_load_lds(
      (const __attribute__((address_space(1))) void*)g,
      (__attribute__((address_space(3))) void*)l, 16, 0, 0);
}

// ---------------- merged preprocessing: f2b(x) + tconv(Wqkv) + tconv(Wout) + invf ------
__global__ __launch_bounds__(256) void k_prep(
    const float* __restrict__ x, bf16* __restrict__ xb,
    const float* __restrict__ Wq, bf16* __restrict__ wqT,
    const float* __restrict__ Wo, bf16* __restrict__ woT,
    float* __restrict__ invf) {
  __shared__ float t[64][65];
  int bid = blockIdx.x;
  int tid = threadIdx.x;
  if (bid < 4096) {                      // f32 -> bf16 convert of x
    long i = ((long)bid * 256 + tid) * 8;
    float4 a = *(const float4*)(x + i);
    float4 b = *(const float4*)(x + i + 4);
    bf16x8 o;
    o[0] = (bf16)a.x; o[1] = (bf16)a.y; o[2] = (bf16)a.z; o[3] = (bf16)a.w;
    o[4] = (bf16)b.x; o[5] = (bf16)b.y; o[6] = (bf16)b.z; o[7] = (bf16)b.w;
    *(bf16x8*)(xb + i) = o;
    return;
  }
  if (bid >= 8192) {                     // RoPE inverse-frequency table
    if (tid < 64) invf[tid] = 1.0f / (float)pow(10000.0, (double)tid / 64.0);
    return;
  }
  const float* in;
  bf16* out;
  int R, C, rb;
  if (bid < 7168) { in = Wq; out = wqT; R = 2048; C = 6144; rb = bid - 4096; }
  else            { in = Wo; out = woT; R = 2048; C = 2048; rb = bid - 7168; }
  int nbc = C >> 6;
  long r0 = (long)(rb / nbc) * 64, c0 = (long)(rb % nbc) * 64;
#pragma unroll
  for (int i = 0; i < 4; ++i) {
    int ch = tid + i * 256;
    int r = ch >> 4, c4 = (ch & 15) * 4;
    float4 v = *(const float4*)(in + (r0 + r) * C + c0 + c4);
    t[r][c4] = v.x; t[r][c4 + 1] = v.y; t[r][c4 + 2] = v.z; t[r][c4 + 3] = v.w;
  }
  __syncthreads();
#pragma unroll
  for (int i = 0; i < 2; ++i) {
    int ch = tid + i * 256;
    int c = ch >> 3, r8 = (ch & 7) * 8;
    bf16x8 o;
#pragma unroll
    for (int j = 0; j < 8; ++j) o[j] = (bf16)t[r8 + j][c];
    *(bf16x8*)(out + (c0 + c) * R + r0 + r8) = o;
  }
}

// ---------------- 8-phase 256x256 QKV GEMM + fused RoPE/RMS/V-transpose epilogue -------
// Template: BK=64, 8 waves (2M x 4N, 128x64 C each), 2 K-tiles/iter, 8 phases/iter.
// Per phase: {ds_read frags; stage 1 half-tile (2 gload_lds); s_barrier; lgkmcnt(0);
// setprio(1) 16 MFMA setprio(0); s_barrier}. Counted vmcnt(4) at phase-0/4 boundaries
// (2 half-tiles in flight), vmcnt(0) only at the final boundary. Chunk-XOR swizzle
// both-sides (R6-proven). __launch_bounds__(512,1): acc[8][4] f32x4 = 128 VGPR must
// NOT spill (R4's (512,2) bound forced spills -> that attempt was scratch-bound).
__global__ __launch_bounds__(512, 1) void k_gemm8q(
    const bf16* __restrict__ A, const bf16* __restrict__ Bt,
    const float* __restrict__ bias,
    const float* __restrict__ invf,
    const float* __restrict__ qw, const float* __restrict__ kw,
    bf16* __restrict__ q_r, bf16* __restrict__ k_r, bf16* __restrict__ v_t) {
  __shared__ __align__(16) bf16 ls[2][2][256 * 64];   // [op A/B][slot][256 rows][64 k]
  int bid = blockIdx.x;
  { int q = gridDim.x >> 3; bid = (bid & 7) * q + (bid >> 3); }  // XCD swizzle (384%8==0)
  const int bm = bid & 15, bn = bid >> 4;   // 16 x 24
  const int tid = threadIdx.x, lane = tid & 63, w = tid >> 6;
  const int wm = w >> 2, wn = w & 3;
  const int fr = lane & 15, fq = lane >> 4;
  const long abase = (long)bm * 256 * 2048;
  const long bbase = (long)bn * 256 * 2048;
  f32x4 acc[8][4] = {};
  bf16x8 bfv[4][2];

  // stage one half-tile (128 rows x 64 k) of op into slot kt&1, half hf
#define STG(op, GP, gb, kt, hf)                                                \
  { _Pragma("unroll") for (int it2 = 0; it2 < 2; ++it2) {                      \
      int g = it2 * 512 + tid;                                                 \
      int rl = g >> 3, u = g & 7;                                              \
      load_lds16(GP + gb + (long)((hf) * 128 + rl) * 2048 + ((kt) << 6)        \
                     + ((u ^ (rl & 7)) << 3),                                  \
                 &ls[op][(kt) & 1][(hf) * 8192 + g * 8]);                      \
  } }

  // one phase: C-quadrant qd (m-frags 2qd,2qd+1) x K-step in slot
#define PH(qd, slot, STGCODE)                                                  \
  {                                                                            \
    bf16x8 afv[2][2];                                                          \
    _Pragma("unroll") for (int mm = 0; mm < 2; ++mm)                           \
      _Pragma("unroll") for (int kk = 0; kk < 2; ++kk) {                       \
        int R = wm * 128 + ((qd) * 2 + mm) * 16 + fr;                          \
        afv[mm][kk] = *(const bf16x8*)&ls[0][slot]                             \
            [R * 64 + (((kk * 4 + fq) ^ (R & 7)) << 3)];                       \
      }                                                                        \
    if ((qd) == 0) {                                                           \
      _Pragma("unroll") for (int nn = 0; nn < 4; ++nn)                         \
        _Pragma("unroll") for (int kk = 0; kk < 2; ++kk) {                     \
          int R = wn * 64 + nn * 16 + fr;                                      \
          bfv[nn][kk] = *(const bf16x8*)&ls[1][slot]                           \
              [R * 64 + (((kk * 4 + fq) ^ (R & 7)) << 3)];                     \
        }                                                                      \
    }                                                                          \
    STGCODE                                                                    \
    __builtin_amdgcn_s_barrier();                                              \
    asm volatile("s_waitcnt lgkmcnt(0)" ::: "memory");                         \
    __builtin_amdgcn_s_setprio(1);                                             \
    _Pragma("unroll") for (int mm = 0; mm < 2; ++mm)                           \
      _Pragma("unroll") for (int nn = 0; nn < 4; ++nn)                         \
        _Pragma("unroll") for (int kk = 0; kk < 2; ++kk)                       \
          acc[(qd) * 2 + mm][nn] = __builtin_amdgcn_mfma_f32_16x16x32_bf16(    \
              afv[mm][kk], bfv[nn][kk], acc[(qd) * 2 + mm][nn], 0, 0, 0);      \
    __builtin_amdgcn_s_setprio(0);                                             \
    __builtin_amdgcn_s_barrier();                                              \
  }

  // prologue: B(0), A(0), B(1)  (12 loads; vmcnt(4) at loop top leaves B(1) in flight)
  STG(1, Bt, bbase, 0, 0) STG(1, Bt, bbase, 0, 1)
  STG(0, A, abase, 0, 0)  STG(0, A, abase, 0, 1)
  STG(1, Bt, bbase, 1, 0) STG(1, Bt, bbase, 1, 1)

  for (int u = 0; u < 16; ++u) {
    const int t = 2 * u;
    asm volatile("s_waitcnt vmcnt(4)" ::: "memory");   // K-tile t fully landed
    __builtin_amdgcn_s_barrier();
    PH(0, 0, STG(0, A, abase, t + 1, 0))
    PH(1, 0, STG(0, A, abase, t + 1, 1))
    PH(2, 0, if (u < 15) { STG(1, Bt, bbase, t + 2, 0) })
    PH(3, 0, if (u < 15) { STG(1, Bt, bbase, t + 2, 1) })
    if (u < 15) { asm volatile("s_waitcnt vmcnt(4)" ::: "memory"); }
    else        { asm volatile("s_waitcnt vmcnt(0)" ::: "memory"); }
    __builtin_amdgcn_s_barrier();                      // K-tile t+1 fully landed
    PH(0, 1, if (u < 15) { STG(0, A, abase, t + 2, 0) })
    PH(1, 1, if (u < 15) { STG(0, A, abase, t + 2, 1) })
    PH(2, 1, if (u < 15) { STG(1, Bt, bbase, t + 3, 0) })
    PH(3, 1, if (u < 15) { STG(1, Bt, bbase, t + 3, 1) })
  }
#undef PH
#undef STG

  // ---------------- fused epilogue: tile = [256 rows][256 cols] bf16 in LDS ----------
  bf16* tile = &ls[0][0][0];            // 128 KB, main loop fully drained
  const int b = bm >> 3, l0 = (bm & 7) << 8;

  if (bn < 16) {
    // q (bn<8) / k: store row-major, col-chunk XOR swizzle
#pragma unroll
    for (int n = 0; n < 4; ++n) {
      int col = wn * 64 + n * 16 + fr;
      float bv = bias[bn * 256 + col];
#pragma unroll
      for (int m = 0; m < 8; ++m)
#pragma unroll
        for (int r = 0; r < 4; ++r) {
          int row = wm * 128 + m * 16 + fq * 4 + r;
          tile[row * 256 + (col ^ ((row & 7) << 3))] = (bf16)(acc[m][n][r] + bv);
        }
    }
    __syncthreads();
    const float* wv = (bn < 8) ? qw : kw;
    bf16* dst0 = (bn < 8) ? q_r : k_r;
    const int tc = tid & 15, hh = (tid >> 4) & 1, rgrp = tid >> 5, i8 = tc * 8;
    const int hg = (bn & 7) * 2 + hh;
    const bool lo = i8 < 64;
    float wvv[8], invv[8];
#pragma unroll
    for (int j = 0; j < 8; ++j) wvv[j] = wv[i8 + j];
#pragma unroll
    for (int j = 0; j < 8; ++j) invv[j] = invf[(i8 + j) & 63];
#pragma unroll
    for (int it = 0; it < 16; ++it) {
      int row = it * 16 + rgrp;
      float fl = (float)(l0 + row);
      float cc[8], sn[8];
#pragma unroll
      for (int j = 0; j < 8; ++j) __sincosf(fl * invv[j], &sn[j], &cc[j]);
      int colb = hh * 128 + i8;
      bf16x8 xv = *(const bf16x8*)&tile[row * 256 + (colb ^ ((row & 7) << 3))];
      float v[8], p[8], rr[8];
      float ss = 0.f;
#pragma unroll
      for (int j = 0; j < 8; ++j) v[j] = (float)xv[j];
#pragma unroll
      for (int j = 0; j < 8; ++j) p[j] = __shfl_xor(v[j], 8);  // d <-> d^64 (tc^8)
#pragma unroll
      for (int j = 0; j < 8; ++j) {
        rr[j] = lo ? v[j] * cc[j] - p[j] * sn[j] : v[j] * cc[j] + p[j] * sn[j];
        ss += rr[j] * rr[j];
      }
      ss += __shfl_xor(ss, 1);
      ss += __shfl_xor(ss, 2);
      ss += __shfl_xor(ss, 4);
      ss += __shfl_xor(ss, 8);
      float inv = rsqrtf(ss * (1.f / 128.f) + 1e-6f);
      bf16x8 ov;
#pragma unroll
      for (int j = 0; j < 8; ++j) ov[j] = (bf16)(rr[j] * inv * wvv[j]);
      *(bf16x8*)(dst0 + ((long)((b * 16 + hg) * 2048 + (l0 + row))) * 128 + i8) = ov;
    }
  } else {
    // v: store transposed [col d][row l], row-chunk XOR swizzle
#pragma unroll
    for (int n = 0; n < 4; ++n) {
      int col = wn * 64 + n * 16 + fr;
      float bv = bias[bn * 256 + col];
#pragma unroll
      for (int m = 0; m < 8; ++m)
#pragma unroll
        for (int r = 0; r < 4; ++r) {
          int row = wm * 128 + m * 16 + fq * 4 + r;
          tile[col * 256 + (row ^ ((col & 7) << 3))] = (bf16)(acc[m][n][r] + bv);
        }
    }
    __syncthreads();
#pragma unroll
    for (int it = 0; it < 16; ++it) {
      int ch = it * 512 + tid;          // 8192 chunks of 16 B = [256 d][32 l-chunks]
      int d = ch >> 5, l8 = (ch & 31) * 8;
      int hg = (bn - 16) * 2 + (d >> 7), dl = d & 127;
      bf16x8 vv = *(const bf16x8*)&tile[d * 256 + (l8 ^ ((d & 7) << 3))];
      *(bf16x8*)(v_t + ((long)((b * 16 + hg) * 128 + dl)) * 2048 + l0 + l8) = vv;
    }
  }
}

// ------- m97-style plain GEMM, BK=64 + XOR-swizzled LDS (R6 proven) — out-proj --------
__global__ __launch_bounds__(256) void k_gemm_bt(
    const bf16* __restrict__ A, const bf16* __restrict__ Bt,
    const float* __restrict__ bias, float* __restrict__ C,
    int M, int N, int K) {
  __shared__ __align__(16) bf16 lA[128 * 64];
  __shared__ __align__(16) bf16 lB[128 * 64];
  int bid = blockIdx.x;
  if ((gridDim.x & 7) == 0) {
    int q = gridDim.x >> 3;
    bid = (bid & 7) * q + (bid >> 3);
  }
  int nbn = N >> 7;
  int bm = bid / nbn, bn = bid % nbn;
  const int tid = threadIdx.x, lane = tid & 63, wid = tid >> 6;
  const int wr = wid >> 1, wc = wid & 1;
  const int fr = lane & 15, fq = lane >> 4;
  const long abase = (long)bm * 128 * K, bbase = (long)bn * 128 * K;
  f32x4 acc[4][4] = {};

  for (int k0 = 0; k0 < K; k0 += 64) {
    __syncthreads();
#pragma unroll
    for (int it = 0; it < 4; ++it) {
      int ch = it * 256 + tid;
      int r = ch >> 3, u = ch & 7;
      load_lds16(A + abase + (long)r * K + k0 + ((u ^ (r & 7)) << 3), &lA[ch * 8]);
    }
#pragma unroll
    for (int it = 0; it < 4; ++it) {
      int ch = it * 256 + tid;
      int r = ch >> 3, u = ch & 7;
      load_lds16(Bt + bbase + (long)r * K + k0 + ((u ^ (r & 7)) << 3), &lB[ch * 8]);
    }
    __syncthreads();
    bf16x8 af[4][2], bf_[4][2];
#pragma unroll
    for (int m = 0; m < 4; ++m) {
      int R = wr * 64 + m * 16 + fr;
#pragma unroll
      for (int kk = 0; kk < 2; ++kk)
        af[m][kk] = *(const bf16x8*)&lA[R * 64 + (((kk * 4 + fq) ^ (R & 7)) << 3)];
    }
#pragma unroll
    for (int n = 0; n < 4; ++n) {
      int R = wc * 64 + n * 16 + fr;
#pragma unroll
      for (int kk = 0; kk < 2; ++kk)
        bf_[n][kk] = *(const bf16x8*)&lB[R * 64 + (((kk * 4 + fq) ^ (R & 7)) << 3)];
    }
#pragma unroll
    for (int m = 0; m < 4; ++m)
#pragma unroll
      for (int n = 0; n < 4; ++n)
#pragma unroll
        for (int kk = 0; kk < 2; ++kk)
          acc[m][n] = __builtin_amdgcn_mfma_f32_16x16x32_bf16(af[m][kk], bf_[n][kk],
                                                              acc[m][n], 0, 0, 0);
  }
#pragma unroll
  for (int n = 0; n < 4; ++n) {
    int col = bn * 128 + wc * 64 + n * 16 + fr;
    float bv = bias[col];
#pragma unroll
    for (int m = 0; m < 4; ++m) {
      int row0 = bm * 128 + wr * 64 + m * 16 + fq * 4;
#pragma unroll
      for (int r = 0; r < 4; ++r)
        C[(long)(row0 + r) * N + col] = acc[m][n][r] + bv;
    }
  }
}

// ---------------- flash attention v9: T15 double-pipeline (R15-proven) -----------------
__global__ __launch_bounds__(512, 1) void k_attn(
    const bf16* __restrict__ q_r, const bf16* __restrict__ k_r,
    const bf16* __restrict__ v_t, const unsigned char* __restrict__ amask,
    bf16* __restrict__ attno) {
  __shared__ __align__(16) bf16 lK[2][64 * 128];   // [kv][dh], XOR-swizzled (16B chunks)
  __shared__ __align__(16) bf16 lV[3][128 * 64];   // [dh][kv], XOR-swizzled
  __shared__ int sAny;
  const int tid = threadIdx.x, lane = tid & 63, w = tid >> 6;
  const int hi = lane >> 5, q31 = lane & 31;
  const int bh = blockIdx.x & 31, qt = blockIdx.x >> 5;   // head-locality swizzle
  const int b = bh >> 4, h = bh & 15;
  const long hbase = (long)bh * 2048 * 128;
  const int q0 = qt * 256 + w * 32;
  const unsigned char* mb = amask + b * 2048;

  if (tid == 0) sAny = 0;
  __syncthreads();
  {
    unsigned mv = *(const unsigned*)(mb + tid * 4);
    if (mv) sAny = 1;
  }

  bf16x8 qf[8];
#pragma unroll
  for (int ksl = 0; ksl < 8; ++ksl)
    qf[ksl] = *(const bf16x8*)(q_r + hbase + (long)(q0 + q31) * 128 + ksl * 16 + hi * 8);

  f32x16 o[4] = {};
  float m_run = -1e30f, l_run = 0.f;
  const float SC2 = 0.08838834764831845f * 1.4426950408889634f;
  const float L2E = 1.4426950408889634f;

#define STAGE_K(buf, kv0)                                                            \
  {                                                                                  \
    _Pragma("unroll") for (int it = 0; it < 2; ++it) {                               \
      int g = it * 512 + w * 64 + lane;                                              \
      int r = g >> 4, u = g & 15;                                                    \
      load_lds16(k_r + hbase + (long)((kv0) + r) * 128 + ((u ^ (r & 7)) << 3),       \
                 &lK[buf][(it * 512 + w * 64) * 8]);                                 \
    }                                                                                \
  }
#define STAGE_V(buf, kv0)                                                            \
  {                                                                                  \
    _Pragma("unroll") for (int it = 0; it < 2; ++it) {                               \
      int g = it * 512 + w * 64 + lane;                                              \
      int r = g >> 3, u = g & 7;                                                     \
      load_lds16(v_t + hbase + (long)r * 2048 + (kv0) + ((u ^ (r & 7)) << 3),        \
                 &lV[buf][(it * 512 + w * 64) * 8]);                                 \
    }                                                                                \
  }

  STAGE_K(0, 0) STAGE_V(0, 0) STAGE_K(1, 64) STAGE_V(1, 64)
  __syncthreads();
  const bool maskAny = sAny != 0;

  f32x16 st0 = {}, st1 = {};
#pragma unroll
  for (int ksl = 0; ksl < 8; ++ksl) {
    const int u = ksl * 2 + hi;
    bf16x8 kf0 = *(const bf16x8*)&lK[0][q31 * 128 + ((u ^ (q31 & 7)) << 3)];
    bf16x8 kf1 = *(const bf16x8*)&lK[0][(32 + q31) * 128 + ((u ^ (q31 & 7)) << 3)];
    st0 = __builtin_amdgcn_mfma_f32_32x32x16_bf16(kf0, qf[ksl], st0, 0, 0, 0);
    st1 = __builtin_amdgcn_mfma_f32_32x32x16_bf16(kf1, qf[ksl], st1, 0, 0, 0);
  }
  __syncthreads();

  for (int t = 0; t < 32; ++t) {
    const int kv0 = t << 6;
    if (t + 2 < 32) {
      STAGE_K(t & 1, kv0 + 128)
      STAGE_V((t + 2) % 3, kv0 + 128)
    }

    f32x16 sn0 = {}, sn1 = {};
    if (t < 31) {
      const bf16* kb = lK[(t + 1) & 1];
#pragma unroll
      for (int ksl = 0; ksl < 8; ++ksl) {
        const int u = ksl * 2 + hi;
        bf16x8 kf0 = *(const bf16x8*)&kb[q31 * 128 + ((u ^ (q31 & 7)) << 3)];
        bf16x8 kf1 = *(const bf16x8*)&kb[(32 + q31) * 128 + ((u ^ (q31 & 7)) << 3)];
        sn0 = __builtin_amdgcn_mfma_f32_32x32x16_bf16(kf0, qf[ksl], sn0, 0, 0, 0);
        sn1 = __builtin_amdgcn_mfma_f32_32x32x16_bf16(kf1, qf[ksl], sn1, 0, 0, 0);
      }
    }

#pragma unroll
    for (int i = 0; i < 16; ++i) { st0[i] *= SC2; st1[i] *= SC2; }
    if (maskAny) {
#pragma unroll
      for (int i = 0; i < 16; ++i) {
        int c = (i & 3) + 8 * (i >> 2) + 4 * hi;
        if (mb[kv0 + c]) st0[i] += L2E;
        if (mb[kv0 + 32 + c]) st1[i] += L2E;
      }
    }
    float tm = st0[0];
#pragma unroll
    for (int i = 1; i < 16; ++i) tm = fmaxf(tm, st0[i]);
#pragma unroll
    for (int i = 0; i < 16; ++i) tm = fmaxf(tm, st1[i]);
    tm = fmaxf(tm, __shfl_xor(tm, 32));

    if (!__all(tm <= m_run + 8.f)) {
      float mn = fmaxf(m_run, tm);
      float corr = exp2f(m_run - mn);
      m_run = mn;
      l_run *= corr;
#pragma unroll
      for (int i = 0; i < 16; ++i) {
        float cr = __shfl(corr, (i & 3) + 8 * (i >> 2) + 4 * hi);
#pragma unroll
        for (int dt = 0; dt < 4; ++dt) o[dt][i] *= cr;
      }
    }

    float rs = 0.f;
#pragma unroll
    for (int i = 0; i < 16; ++i) { st0[i] = exp2f(st0[i] - m_run); rs += st0[i]; }
#pragma unroll
    for (int i = 0; i < 16; ++i) { st1[i] = exp2f(st1[i] - m_run); rs += st1[i]; }
    rs += __shfl_xor(rs, 32);
    l_run += rs;

    union UU { bf16x4 v; uint2 u; };
    union U8 { bf16x8 v; uint4 u; };
    bf16x8 pa[4];
#define MKPA(pidx, STX, bb)                                                          \
  {                                                                                  \
    UU plo, phi;                                                                     \
    plo.v = (bf16x4){(bf16)STX[bb], (bf16)STX[(bb) + 1], (bf16)STX[(bb) + 2],        \
                     (bf16)STX[(bb) + 3]};                                           \
    phi.v = (bf16x4){(bf16)STX[(bb) + 4], (bf16)STX[(bb) + 5], (bf16)STX[(bb) + 6],  \
                     (bf16)STX[(bb) + 7]};                                           \
    unsigned sx = hi ? plo.u.x : phi.u.x, sy = hi ? plo.u.y : phi.u.y;               \
    unsigned rx = (unsigned)__shfl_xor((int)sx, 32), ry = (unsigned)__shfl_xor((int)sy, 32); \
    U8 f;                                                                            \
    f.u.x = hi ? rx : plo.u.x; f.u.y = hi ? ry : plo.u.y;                            \
    f.u.z = hi ? phi.u.x : rx; f.u.w = hi ? phi.u.y : ry;                            \
    pa[pidx] = f.v;                                                                  \
  }
    MKPA(0, st0, 0) MKPA(1, st0, 8) MKPA(2, st1, 0) MKPA(3, st1, 8)
#undef MKPA

    const bf16* vb3 = lV[t % 3];
#pragma unroll
    for (int dt = 0; dt < 4; ++dt) {
      const int dr = dt * 32 + q31;
#pragma unroll
      for (int ks = 0; ks < 4; ++ks) {
        const int u = ks * 2 + hi;
        bf16x8 vb = *(const bf16x8*)&vb3[dr * 64 + ((u ^ (dr & 7)) << 3)];
        o[dt] = __builtin_amdgcn_mfma_f32_32x32x16_bf16(pa[ks], vb, o[dt], 0, 0, 0);
      }
    }

    __syncthreads();
    st0 = sn0;
    st1 = sn1;
  }
#undef STAGE_K
#undef STAGE_V

  float invl = 1.f / l_run;
#pragma unroll
  for (int i = 0; i < 16; ++i) {
    int q = (i & 3) + 8 * (i >> 2) + 4 * hi;
    int qrow = q0 + q;
    float inv = __shfl(invl, q);
    float zm = inv;
    if (maskAny) { if (mb[qrow]) zm = 0.f; }
#pragma unroll
    for (int dt = 0; dt < 4; ++dt)
      attno[(long)(b * 2048 + qrow) * 2048 + h * 128 + dt * 32 + q31] = (bf16)(o[dt][i] * zm);
  }
}

extern "C" void kernel_launch(void* const* d_in, const int* in_sizes, int n_in,
                              void* d_out, int out_size, void* d_ws, size_t ws_size,
                              hipStream_t stream) {
  const float* x = (const float*)d_in[0];
  const unsigned char* amask = (const unsigned char*)d_in[1];
  const float* Wqkv = (const float*)d_in[2];
  const float* bqkv = (const float*)d_in[3];
  const float* Wout = (const float*)d_in[4];
  const float* bout = (const float*)d_in[5];
  const float* qw = (const float*)d_in[6];
  const float* kw = (const float*)d_in[7];
  float* out = (float*)d_out;
  char* ws = (char*)d_ws;

  bf16* xb   = (bf16*)(ws);                         // 16 MB (reused as attnout later)
  bf16* wqT  = (bf16*)(ws + 16777216);              // 24 MB  Wqkv^T [6144][2048]
  bf16* woT  = (bf16*)(ws + 41943040);              // 8 MB   Wout^T [2048][2048]
  bf16* q_r  = (bf16*)(ws + 100663296);             // 16 MB  [B*H,L,DH]
  bf16* k_r  = (bf16*)(ws + 117440512);             // 16 MB
  bf16* v_t  = (bf16*)(ws + 134217728);             // 16 MB  [B*H,DH,L]
  float* invf = (float*)(ws + 150994944);           // 256 B
  bf16* attno = xb;  // alias: x_bf16 dead after QKV GEMM

  k_prep<<<8193, 256, 0, stream>>>(x, xb, Wqkv, wqT, Wout, woT, invf);
  k_gemm8q<<<384, 512, 0, stream>>>(xb, wqT, bqkv, invf, qw, kw, q_r, k_r, v_t);
  k_attn<<<256, 512, 0, stream>>>(q_r, k_r, v_t, amask, attno);
  k_gemm_bt<<<32 * 16, 256, 0, stream>>>(attno, woT, bout, out, 4096, 2048, 2048);
}